// Round 17
// baseline (141.683 us; speedup 1.0000x reference)
//
#include <hip/hip_runtime.h>
#include <hip/hip_bf16.h>
#include <hip/hip_fp16.h>

// ---------------- problem constants ----------------
constexpr int NB = 16;       // batch
constexpr int SS = 64;       // seq len
constexpr int BS = 1024;     // NB*SS
constexpr int NN = 500;      // nodes
constexpr int FF = 32;       // gat out features
constexpr int EE = 8000;     // edges (without self loops)
constexpr int ET = 8500;     // edges + self loops
constexpr int KK = 16000;    // NN*FF  (lstm input size)
constexpr int HH = 128;      // lstm hidden
constexpr int GG = 512;      // 4*HH
constexpr int KS = 16;       // K-split for the big GEMM (250 steps of 64k)

typedef __attribute__((ext_vector_type(8))) _Float16 f16x8;
typedef __attribute__((ext_vector_type(2))) _Float16 f16x2;
typedef __attribute__((ext_vector_type(4))) float f32x4;

__device__ __forceinline__ void gload_lds16(const void* g, void* l) {
    __builtin_amdgcn_global_load_lds((const __attribute__((address_space(1))) void*)g,
                                     (__attribute__((address_space(3))) void*)l, 16, 0, 0);
}

__device__ __forceinline__ float fast_sigmoid(float x) {
    return __builtin_amdgcn_rcpf(1.f + __expf(-x));
}

__device__ __forceinline__ float fdot2(f16x2 a, f16x2 b, float c) {
#if __has_builtin(__builtin_amdgcn_fdot2)
    return __builtin_amdgcn_fdot2(a, b, c, false);
#else
    float r;
    asm("v_dot2_f32_f16 %0, %1, %2, %3" : "=v"(r) : "v"(a), "v"(b), "v"(c));
    return r;
#endif
}

// AGPR weight residency: the VALU allocator never demotes AGPR-held values
// (plain code can't use AGPRs -> zero pressure). asm volatile outputs can't
// be remat'd or sunk into the loop — the failure modes of r10-r16 where
// VGPR-held weights were always refetched from L2/scratch each step.
__device__ __forceinline__ void agpr_write(uint32_t& a, uint32_t v) {
    asm volatile("v_accvgpr_write_b32 %0, %1" : "=a"(a) : "v"(v));
}
__device__ __forceinline__ f16x2 agpr_read(const uint32_t& a) {
    uint32_t v;
    asm volatile("v_accvgpr_read_b32 %0, %1" : "=v"(v) : "a"(a));
    union { uint32_t u; f16x2 h; } c;
    c.u = v;
    return c.h;
}

// quad-lane butterfly add via DPP (full-rate VALU, no LDS). CTRL is an ICE.
template <int CTRL>
__device__ __forceinline__ float dpp_add(float x) {
    int y = __builtin_amdgcn_mov_dpp(__float_as_int(x), CTRL, 0xF, 0xF, true);
    return x + __int_as_float(y);
}

// LDS-only barrier: no memory clobber -> no vmcnt(0) drain; sched_barrier(0)
// pins ordering (guide rule #18).
__device__ __forceinline__ void lds_barrier() {
    __builtin_amdgcn_sched_barrier(0);
    asm volatile("s_waitcnt lgkmcnt(0)");
    __builtin_amdgcn_sched_barrier(0);
    __builtin_amdgcn_s_barrier();
    __builtin_amdgcn_sched_barrier(0);
}

// ---------------- fused prep: transpose_x | whh->fp16 | w_ih->fp16 swizzled ----------------
__global__ __launch_bounds__(256) void k_prep(const float* __restrict__ x, float* __restrict__ xt,
                                              const float* __restrict__ whh,
                                              _Float16* __restrict__ whh_h,
                                              const float* __restrict__ w_ih,
                                              _Float16* __restrict__ w_h) {
    __shared__ float tile[32][33];
    int bid = blockIdx.x;
    int tid = threadIdx.x;
    if (bid < 512) {
        // xt[n][bs] = x[bs][n]
        int n0 = (bid & 15) * 32, bs0 = (bid >> 4) * 32;
        int tx = tid & 31, ty = tid >> 5;  // 32 x 8
#pragma unroll
        for (int i = 0; i < 4; ++i) {
            int n = n0 + tx, bs = bs0 + ty + i * 8;
            tile[ty + i * 8][tx] = (n < NN) ? x[bs * NN + n] : 0.f;
        }
        __syncthreads();
#pragma unroll
        for (int i = 0; i < 4; ++i) {
            int n = n0 + ty + i * 8, bs = bs0 + tx;
            if (n < NN) xt[n * BS + bs] = tile[tx][ty + i * 8];
        }
    } else if (bid < 768) {
        // whh [512][128] fp32 -> fp16 (same layout)
        int idx = (bid - 512) * 256 + tid;  // 65536
        whh_h[idx] = (_Float16)whh[idx];
    } else {
        // w_h[g][blk*64 + sl*8 + j] = (fp16) w_ih[g][blk*64 + (sl^(g&7))*8 + j]
        int r = bid - 768;            // 0..4095
        int g = r >> 3;               // 512 rows
        int id = (r & 7) * 256 + tid; // 0..2047, 2000 used
        if (id < 2000) {
            int blk = id >> 3, sl = id & 7;
            int srcc = sl ^ (g & 7);
            const float* src = w_ih + (size_t)g * KK + blk * 64 + srcc * 8;
            float4 v0 = *(const float4*)src;
            float4 v1 = *(const float4*)(src + 4);
            union { __half2 h2[4]; uint4 q; } u;
            u.h2[0] = __floats2half2_rn(v0.x, v0.y);
            u.h2[1] = __floats2half2_rn(v0.z, v0.w);
            u.h2[2] = __floats2half2_rn(v1.x, v1.y);
            u.h2[3] = __floats2half2_rn(v1.z, v1.w);
            *(uint4*)(w_h + (size_t)g * KK + blk * 64 + sl * 8) = u.q;
        }
    }
}

// ---------------- fused graph build: count -> scan -> scatter (1 block) ----------------
__global__ __launch_bounds__(512) void k_graph(const int* __restrict__ ei,
                                               const float* __restrict__ gat_w,
                                               const float* __restrict__ a_src,
                                               const float* __restrict__ a_dst,
                                               int* __restrict__ offsets,
                                               int* __restrict__ esrc,
                                               float* __restrict__ scal) {
    __shared__ int cnt[512];
    __shared__ int sc[2][512];
    __shared__ int cur[512];
    int t = threadIdx.x;  // 512
    cnt[t] = 0;
    __syncthreads();
    for (int e = t; e < ET; e += 512) {
        int d = (e < EE) ? ei[EE + e] : (e - EE);
        atomicAdd(&cnt[d], 1);
    }
    __syncthreads();
    sc[0][t] = cnt[t];
    __syncthreads();
    int pb = 0;
    for (int off = 1; off < 512; off <<= 1) {
        int v = sc[pb][t];
        if (t >= off) v += sc[pb][t - off];
        sc[pb ^ 1][t] = v;
        pb ^= 1;
        __syncthreads();
    }
    int excl = sc[pb][t] - cnt[t];
    if (t <= NN) offsets[t] = excl;
    cur[t] = excl;
    if (t == 0) {
        float ws = 0.f, wd = 0.f;
        for (int f = 0; f < FF; ++f) {
            ws += gat_w[f] * a_src[f];
            wd += gat_w[f] * a_dst[f];
        }
        scal[0] = ws;
        scal[1] = wd;
    }
    __syncthreads();
    for (int e = t; e < ET; e += 512) {
        int sidx = (e < EE) ? ei[e] : (e - EE);
        int d = (e < EE) ? ei[EE + e] : (e - EE);
        int pos = atomicAdd(&cur[d], 1);
        esrc[pos] = sidx;
    }
}

// ---------------- GAT: per-(n,bs) edge softmax -> s[n][bs] ----------------
__global__ void k_gat(const float* __restrict__ xt, const int* __restrict__ offsets,
                      const int* __restrict__ esrc, const float* __restrict__ scal,
                      float* __restrict__ s) {
    int n = blockIdx.y;
    int bs = blockIdx.x * 256 + threadIdx.x;
    float ws = scal[0], wd = scal[1];
    float xd = xt[n * BS + bs];
    float wdxd = wd * xd;
    int e0 = offsets[n], e1 = offsets[n + 1];
    float m = -1e30f, den = 0.f, num = 0.f;
    for (int j = e0; j < e1; ++j) {
        int sidx = esrc[j];  // uniform across wave
        float xs = xt[sidx * BS + bs];
        float z = ws * xs + wdxd;
        float l = (z > 0.f) ? z : 0.2f * z;  // leaky_relu 0.2
        if (l > m) {
            float r = __expf(m - l);
            den *= r;
            num *= r;
            m = l;
        }
        float p = __expf(l - m);
        den += p;
        num += p * xs;
    }
    s[n * BS + bs] = num / den;
}

// ---------------- big GEMM via fp16 MFMA ----------------
__global__ __launch_bounds__(256, 2) void k_gemm_mfma(
    const _Float16* __restrict__ w_h, const float* __restrict__ s,
    const float* __restrict__ gat_w, const float* __restrict__ gat_b,
    float* __restrict__ G2) {
    __shared__ __align__(16) _Float16 Bs[2][128 * 64];  // [buf][g][k] swizzled image
    __shared__ float s_lds[2][2][128];                  // [buf][node][bs_local]

    int tid = threadIdx.x;
    int lane = tid & 63;
    int w = tid >> 6;
    int wm = w >> 1, wn = w & 1;
    int bm = blockIdx.x, bn = blockIdx.y, ks = blockIdx.z;
    int bs0 = bm * 128, g0 = bn * 128;
    int step0 = (ks * 250) >> 4;
    int nst = (((ks + 1) * 250) >> 4) - step0;  // 15 or 16

    int fbase = (lane >> 4) * 8;
    float w8[8], b8[8];
#pragma unroll
    for (int j = 0; j < 8; ++j) {
        w8[j] = gat_w[fbase + j];
        b8[j] = gat_b[fbase + j];
    }

    f32x4 acc[4][4] = {};

    auto stageB = [&](int buf, int stepg) {
#pragma unroll
        for (int qq = 0; qq < 4; ++qq) {
            int q = w * 4 + qq;
            int row_local = q * 8 + (lane >> 3);
            int sl = lane & 7;
            const _Float16* srcp = w_h + (size_t)(g0 + row_local) * KK + stepg * 64 + sl * 8;
            gload_lds16(srcp, &Bs[buf][q * 512]);
        }
        int row = tid >> 7, col = tid & 127;
        int n = 2 * stepg + row;
        s_lds[buf][row][col] = s[n * BS + bs0 + col];
    };

    auto compute = [&](int buf) {
#pragma unroll
        for (int kh = 0; kh < 2; ++kh) {
            f16x8 bfrag[4];
#pragma unroll
            for (int fn = 0; fn < 4; ++fn) {
                int grow = wn * 64 + fn * 16 + (lane & 15);
                int c = kh * 4 + (lane >> 4);
                int slot = c ^ (grow & 7);
                bfrag[fn] = *(const f16x8*)&Bs[buf][grow * 64 + slot * 8];
            }
#pragma unroll
            for (int fm = 0; fm < 4; ++fm) {
                float sval = s_lds[buf][kh][wm * 64 + fm * 16 + (lane & 15)];
                union { f16x8 v; __half2 h2[4]; } af;
#pragma unroll
                for (int j2 = 0; j2 < 4; ++j2) {
                    float t0 = fmaf(sval, w8[2 * j2], b8[2 * j2]);
                    float t1 = fmaf(sval, w8[2 * j2 + 1], b8[2 * j2 + 1]);
                    t0 = t0 > 0.f ? t0 : 0.f;
                    t1 = t1 > 0.f ? t1 : 0.f;
                    af.h2[j2] = __floats2half2_rn(t0, t1);
                }
#pragma unroll
                for (int fn = 0; fn < 4; ++fn) {
                    acc[fm][fn] =
                        __builtin_amdgcn_mfma_f32_16x16x32_f16(af.v, bfrag[fn], acc[fm][fn], 0, 0, 0);
                }
            }
        }
    };

    stageB(0, step0);
    __syncthreads();
    for (int t = 0; t < nst; ++t) {
        if (t + 1 < nst) stageB((t + 1) & 1, step0 + t + 1);
        compute(t & 1);
        __syncthreads();
    }

    float* Gks = G2 + (size_t)ks * BS * GG;
#pragma unroll
    for (int fm = 0; fm < 4; ++fm) {
#pragma unroll
        for (int fn = 0; fn < 4; ++fn) {
            int bs = bs0 + wm * 64 + fm * 16 + ((lane >> 4) << 2);
            int g = g0 + wn * 64 + fn * 16 + (lane & 15);
            float* base = Gks + (size_t)bs * GG + g;
#pragma unroll
            for (int r = 0; r < 4; ++r) base[r * GG] = acc[fm][fn][r];
        }
    }
}

// ---------------- reduce K-split partials + biases -> Xg[bs][512] ----------------
__global__ __launch_bounds__(256) void k_reduce(const float* __restrict__ G2,
                                                const float* __restrict__ b_ih,
                                                const float* __restrict__ b_hh,
                                                float* __restrict__ Xg) {
    int idx = blockIdx.x * 256 + threadIdx.x;  // 131072 float4 slots
    int e = idx * 4;
    int g = e & (GG - 1);
    float4 acc = *(const float4*)&b_ih[g];
    float4 bh = *(const float4*)&b_hh[g];
    acc.x += bh.x; acc.y += bh.y; acc.z += bh.z; acc.w += bh.w;
#pragma unroll
    for (int p = 0; p < KS; ++p) {
        float4 v = *(const float4*)&G2[(size_t)p * BS * GG + e];
        acc.x += v.x; acc.y += v.y; acc.z += v.z; acc.w += v.w;
    }
    *(float4*)&Xg[e] = acc;
}

// ---------------- LSTM: 16 blocks, 512 thr, AGPR-resident weights ----------------
// Thread (d = tid>>2, kc = tid&3) owns gates {i,f,g,o} of hidden dim d over
// K-chunk [kc*32, +32). Weights (64 dwords/thread) are parked in AGPRs via
// v_accvgpr_write before the loop and pulled with v_accvgpr_read at use —
// the VALU register allocator can't demote AGPR values (r10-r16: VGPR-held
// weights were ALWAYS refetched from L2/scratch, ~1100 cyc/step).
// Quad-DPP butterfly reduce; one lds_barrier/step; double-buffered h.
__global__ __launch_bounds__(512, 1) void k_lstm_agpr(const float* __restrict__ Xg,
                                                      const _Float16* __restrict__ whh_h,
                                                      const float* __restrict__ head_w,
                                                      const float* __restrict__ head_b,
                                                      float* __restrict__ out) {
    __shared__ __align__(16) _Float16 hb0[HH];
    __shared__ __align__(16) _Float16 hb1[HH];
    __shared__ __align__(16) float hf[HH];

    int tid = threadIdx.x;
    int b = blockIdx.x;
    int d = tid >> 2;   // 0..127
    int kc = tid & 3;   // 0..3
    int k0 = kc * 32;

    union U8 { f16x8 v; f16x2 h[4]; uint32_t u[4]; };

    // park weights in AGPRs: wa[q*16 + j*4 + p] = dword p of Whh[q*128+d][k0+j*8..]
    uint32_t wa[64];
#pragma unroll
    for (int q = 0; q < 4; ++q)
#pragma unroll
        for (int j = 0; j < 4; ++j) {
            U8 v;
            v.v = *(const f16x8*)&whh_h[(q * HH + d) * HH + k0 + j * 8];
#pragma unroll
            for (int p = 0; p < 4; ++p) agpr_write(wa[q * 16 + j * 4 + p], v.u[p]);
        }

    if (tid < HH) hb0[tid] = (_Float16)0.f;
    float c = 0.f;
    float xg[4];
#pragma unroll
    for (int q = 0; q < 4; ++q) xg[q] = Xg[(size_t)(b * SS) * GG + q * HH + d];
    __syncthreads();

    auto lstm_step = [&](const _Float16* hr, _Float16* hw, int t) {
        // h chunk: quad lanes read 4 distinct 16B lines; same-kc lanes broadcast
        U8 hh[4];
#pragma unroll
        for (int j = 0; j < 4; ++j) hh[j].v = *(const f16x8*)&hr[k0 + j * 8];
        float acc[4] = {0.f, 0.f, 0.f, 0.f};
#pragma unroll
        for (int j = 0; j < 4; ++j)
#pragma unroll
            for (int p = 0; p < 4; ++p) {
#pragma unroll
                for (int q = 0; q < 4; ++q)
                    acc[q] = fdot2(hh[j].h[p], agpr_read(wa[q * 16 + j * 4 + p]), acc[q]);
            }
        // quad butterfly: acc -> full K sum in every lane of the quad
#pragma unroll
        for (int q = 0; q < 4; ++q) {
            acc[q] = dpp_add<0xB1>(acc[q]);  // quad_perm [1,0,3,2] : xor 1
            acc[q] = dpp_add<0x4E>(acc[q]);  // quad_perm [2,3,0,1] : xor 2
        }
        float ig = acc[0] + xg[0];
        float fg = acc[1] + xg[1];
        float gg = acc[2] + xg[2];
        float og = acc[3] + xg[3];
        // prefetch next step's xg (hidden under this step's tail + barrier)
        int tn = (t + 1) & 63;
#pragma unroll
        for (int q = 0; q < 4; ++q)
            xg[q] = Xg[(size_t)(b * SS + tn) * GG + q * HH + d];
        // all quad lanes compute nonlin redundantly (no specialization phase)
        // c = sig(f)c + sig(i)tanh(g); h = sig(o)tanh(c)
        // sig(a)tanh(b) = sign(b)(1-w)rcp((1+u)(1+w)), u=e^-a, w=e^-2|b|
        float sf = fast_sigmoid(fg);
        float u = __expf(-ig);
        float wv = __expf(-2.f * fabsf(gg));
        float st = copysignf((1.f - wv) * __builtin_amdgcn_rcpf((1.f + u) * (1.f + wv)), gg);
        c = sf * c + st;
        float u2 = __expf(-og);
        float w2 = __expf(-2.f * fabsf(c));
        float h = copysignf((1.f - w2) * __builtin_amdgcn_rcpf((1.f + u2) * (1.f + w2)), c);
        if (kc == 0) {
            hw[d] = (_Float16)h;
            if (t == SS - 1) hf[d] = h;
        }
        lds_barrier();  // one barrier/step; xg global prefetch stays in flight
    };

    for (int tt = 0; tt < SS; tt += 2) {
        lstm_step(hb0, hb1, tt);
        lstm_step(hb1, hb0, tt + 1);
    }

    __syncthreads();
    // fused head: out[b][n] = head_b[n] + sum_d hf[d]*head_w[n][d]
    if (tid < NN) {
        float a0 = head_b[tid], a1 = 0.f, a2 = 0.f, a3 = 0.f;
        const float4* w4 = (const float4*)&head_w[tid * HH];
        const float4* h4 = (const float4*)hf;
#pragma unroll
        for (int j4 = 0; j4 < 32; ++j4) {
            float4 wv = w4[j4];
            float4 hv = h4[j4];
            a0 = fmaf(wv.x, hv.x, a0);
            a1 = fmaf(wv.y, hv.y, a1);
            a2 = fmaf(wv.z, hv.z, a2);
            a3 = fmaf(wv.w, hv.w, a3);
        }
        out[b * NN + tid] = (a0 + a1) + (a2 + a3);
    }
}

// ---------------- launch ----------------
extern "C" void kernel_launch(void* const* d_in, const int* in_sizes, int n_in, void* d_out,
                              int out_size, void* d_ws, size_t ws_size, hipStream_t stream) {
    const float* x = (const float*)d_in[0];
    const int* ei = (const int*)d_in[1];  // integer inputs arrive as int32
    const float* gat_w = (const float*)d_in[2];
    const float* a_src = (const float*)d_in[3];
    const float* a_dst = (const float*)d_in[4];
    const float* gat_b = (const float*)d_in[5];
    const float* w_ih = (const float*)d_in[6];
    const float* w_hh = (const float*)d_in[7];
    const float* b_ih = (const float*)d_in[8];
    const float* b_hh = (const float*)d_in[9];
    const float* head_w = (const float*)d_in[10];
    const float* head_b = (const float*)d_in[11];
    float* out = (float*)d_out;

    char* ws = (char*)d_ws;
    float* xt = (float*)(ws + 0);                      // 2,048,000 (dead after k_gat)
    float* s = (float*)(ws + 2048000u);                // 2,048,000 (dead after k_gemm)
    float* G2 = (float*)(ws + 4096000u);               // 16*1024*512*4 = 33,554,432
    _Float16* whh_h = (_Float16*)(ws + 37650432u);     // 131,072
    _Float16* w_h = (_Float16*)(ws + 37912576u);       // 16,384,000
    char* base2 = ws + 54296576u;                      // misc 65,536
    int* offsets = (int*)(base2);
    int* esrc = (int*)(base2 + 4096);
    float* scal = (float*)(base2 + 45056);
    float* Xg = (float*)(ws + 0);                      // 2,097,152 [bs][512] — overlaps xt+s
                                                       // (both dead by k_reduce; stream-ordered)

    k_prep<<<4864, 256, 0, stream>>>(x, xt, w_hh, whh_h, w_ih, w_h);
    k_graph<<<1, 512, 0, stream>>>(ei, gat_w, a_src, a_dst, offsets, esrc, scal);
    k_gat<<<dim3(BS / 256, NN), 256, 0, stream>>>(xt, offsets, esrc, scal, s);
    k_gemm_mfma<<<dim3(8, 4, KS), 256, 0, stream>>>(w_h, s, gat_w, gat_b, G2);
    k_reduce<<<512, 256, 0, stream>>>(G2, b_ih, b_hh, Xg);
    k_lstm_agpr<<<NB, 512, 0, stream>>>(Xg, whh_h, head_w, head_b, out);
}

// Round 18
// 137.161 us; speedup vs baseline: 1.0330x; 1.0330x over previous
//
#include <hip/hip_runtime.h>
#include <hip/hip_bf16.h>
#include <hip/hip_fp16.h>

// ---------------- problem constants ----------------
constexpr int NB = 16;       // batch
constexpr int SS = 64;       // seq len
constexpr int BS = 1024;     // NB*SS
constexpr int NN = 500;      // nodes
constexpr int FF = 32;       // gat out features
constexpr int EE = 8000;     // edges (without self loops)
constexpr int ET = 8500;     // edges + self loops
constexpr int KK = 16000;    // NN*FF  (lstm input size)
constexpr int HH = 128;      // lstm hidden
constexpr int GG = 512;      // 4*HH
constexpr int KS = 8;        // K-split for the big GEMM (250 steps of 64k)

typedef __attribute__((ext_vector_type(8))) _Float16 f16x8;
typedef __attribute__((ext_vector_type(2))) _Float16 f16x2;
typedef __attribute__((ext_vector_type(4))) float f32x4;

__device__ __forceinline__ void gload_lds16(const void* g, void* l) {
    __builtin_amdgcn_global_load_lds((const __attribute__((address_space(1))) void*)g,
                                     (__attribute__((address_space(3))) void*)l, 16, 0, 0);
}

__device__ __forceinline__ float fast_sigmoid(float x) {
    return __builtin_amdgcn_rcpf(1.f + __expf(-x));
}

__device__ __forceinline__ float fdot2(f16x2 a, f16x2 b, float c) {
#if __has_builtin(__builtin_amdgcn_fdot2)
    return __builtin_amdgcn_fdot2(a, b, c, false);
#else
    float r;
    asm("v_dot2_f32_f16 %0, %1, %2, %3" : "=v"(r) : "v"(a), "v"(b), "v"(c));
    return r;
#endif
}

// quad-lane butterfly add via DPP (full-rate VALU, no LDS). CTRL is an ICE.
template <int CTRL>
__device__ __forceinline__ float dpp_add(float x) {
    int y = __builtin_amdgcn_mov_dpp(__float_as_int(x), CTRL, 0xF, 0xF, true);
    return x + __int_as_float(y);
}

// LDS-only barrier: no memory clobber -> no vmcnt(0) drain; sched_barrier(0)
// pins ordering (guide rule #18).
__device__ __forceinline__ void lds_barrier() {
    __builtin_amdgcn_sched_barrier(0);
    asm volatile("s_waitcnt lgkmcnt(0)");
    __builtin_amdgcn_sched_barrier(0);
    __builtin_amdgcn_s_barrier();
    __builtin_amdgcn_sched_barrier(0);
}

// ---------------- fused prep: transpose_x | whh->fp16 | w_ih->fp16 swizzled ----------------
__global__ __launch_bounds__(256) void k_prep(const float* __restrict__ x, float* __restrict__ xt,
                                              const float* __restrict__ whh,
                                              _Float16* __restrict__ whh_h,
                                              const float* __restrict__ w_ih,
                                              _Float16* __restrict__ w_h) {
    __shared__ float tile[32][33];
    int bid = blockIdx.x;
    int tid = threadIdx.x;
    if (bid < 512) {
        // xt[n][bs] = x[bs][n]
        int n0 = (bid & 15) * 32, bs0 = (bid >> 4) * 32;
        int tx = tid & 31, ty = tid >> 5;  // 32 x 8
#pragma unroll
        for (int i = 0; i < 4; ++i) {
            int n = n0 + tx, bs = bs0 + ty + i * 8;
            tile[ty + i * 8][tx] = (n < NN) ? x[bs * NN + n] : 0.f;
        }
        __syncthreads();
#pragma unroll
        for (int i = 0; i < 4; ++i) {
            int n = n0 + ty + i * 8, bs = bs0 + tx;
            if (n < NN) xt[n * BS + bs] = tile[tx][ty + i * 8];
        }
    } else if (bid < 768) {
        // whh [512][128] fp32 -> fp16 (same layout)
        int idx = (bid - 512) * 256 + tid;  // 65536
        whh_h[idx] = (_Float16)whh[idx];
    } else {
        // w_h[g][blk*64 + sl*8 + j] = (fp16) w_ih[g][blk*64 + (sl^(g&7))*8 + j]
        int r = bid - 768;            // 0..4095
        int g = r >> 3;               // 512 rows
        int id = (r & 7) * 256 + tid; // 0..2047, 2000 used
        if (id < 2000) {
            int blk = id >> 3, sl = id & 7;
            int srcc = sl ^ (g & 7);
            const float* src = w_ih + (size_t)g * KK + blk * 64 + srcc * 8;
            float4 v0 = *(const float4*)src;
            float4 v1 = *(const float4*)(src + 4);
            union { __half2 h2[4]; uint4 q; } u;
            u.h2[0] = __floats2half2_rn(v0.x, v0.y);
            u.h2[1] = __floats2half2_rn(v0.z, v0.w);
            u.h2[2] = __floats2half2_rn(v1.x, v1.y);
            u.h2[3] = __floats2half2_rn(v1.z, v1.w);
            *(uint4*)(w_h + (size_t)g * KK + blk * 64 + sl * 8) = u.q;
        }
    }
}

// ---------------- fused graph build: count -> scan -> scatter (1 block) ----------------
__global__ __launch_bounds__(512) void k_graph(const int* __restrict__ ei,
                                               const float* __restrict__ gat_w,
                                               const float* __restrict__ a_src,
                                               const float* __restrict__ a_dst,
                                               int* __restrict__ offsets,
                                               int* __restrict__ esrc,
                                               float* __restrict__ scal) {
    __shared__ int cnt[512];
    __shared__ int sc[2][512];
    __shared__ int cur[512];
    int t = threadIdx.x;  // 512
    cnt[t] = 0;
    __syncthreads();
    for (int e = t; e < ET; e += 512) {
        int d = (e < EE) ? ei[EE + e] : (e - EE);
        atomicAdd(&cnt[d], 1);
    }
    __syncthreads();
    sc[0][t] = cnt[t];
    __syncthreads();
    int pb = 0;
    for (int off = 1; off < 512; off <<= 1) {
        int v = sc[pb][t];
        if (t >= off) v += sc[pb][t - off];
        sc[pb ^ 1][t] = v;
        pb ^= 1;
        __syncthreads();
    }
    int excl = sc[pb][t] - cnt[t];
    if (t <= NN) offsets[t] = excl;
    cur[t] = excl;
    if (t == 0) {
        float ws = 0.f, wd = 0.f;
        for (int f = 0; f < FF; ++f) {
            ws += gat_w[f] * a_src[f];
            wd += gat_w[f] * a_dst[f];
        }
        scal[0] = ws;
        scal[1] = wd;
    }
    __syncthreads();
    for (int e = t; e < ET; e += 512) {
        int sidx = (e < EE) ? ei[e] : (e - EE);
        int d = (e < EE) ? ei[EE + e] : (e - EE);
        int pos = atomicAdd(&cur[d], 1);
        esrc[pos] = sidx;
    }
}

// ---------------- GAT: per-(n, 4 bs) edge softmax -> s[n][bs] ----------------
// Each thread handles 4 consecutive bs via float4 (amortizes the serial edge
// loop 4x; 500 blocks instead of 2000).
__global__ __launch_bounds__(256) void k_gat(const float* __restrict__ xt,
                                             const int* __restrict__ offsets,
                                             const int* __restrict__ esrc,
                                             const float* __restrict__ scal,
                                             float* __restrict__ s) {
    int n = blockIdx.x;
    int bs = threadIdx.x * 4;
    float ws = scal[0], wd = scal[1];
    float4 xd = *(const float4*)&xt[n * BS + bs];
    float wx0 = wd * xd.x, wx1 = wd * xd.y, wx2 = wd * xd.z, wx3 = wd * xd.w;
    int e0 = offsets[n], e1 = offsets[n + 1];
    float m0 = -1e30f, m1 = -1e30f, m2 = -1e30f, m3 = -1e30f;
    float d0 = 0.f, d1 = 0.f, d2 = 0.f, d3 = 0.f;
    float u0 = 0.f, u1 = 0.f, u2 = 0.f, u3 = 0.f;
    for (int j = e0; j < e1; ++j) {
        int sidx = esrc[j];  // uniform across wave
        float4 xs = *(const float4*)&xt[sidx * BS + bs];
#define GAT_LANE(mq, dq, uq, xv, wxq)                                  \
        {                                                              \
            float z = ws * (xv) + (wxq);                               \
            float l = (z > 0.f) ? z : 0.2f * z;                        \
            if (l > mq) {                                              \
                float r = __expf(mq - l);                              \
                dq *= r; uq *= r; mq = l;                              \
            }                                                          \
            float p = __expf(l - mq);                                  \
            dq += p; uq += p * (xv);                                   \
        }
        GAT_LANE(m0, d0, u0, xs.x, wx0)
        GAT_LANE(m1, d1, u1, xs.y, wx1)
        GAT_LANE(m2, d2, u2, xs.z, wx2)
        GAT_LANE(m3, d3, u3, xs.w, wx3)
#undef GAT_LANE
    }
    float4 r = {u0 / d0, u1 / d1, u2 / d2, u3 / d3};
    *(float4*)&s[n * BS + bs] = r;
}

// ---------------- big GEMM via fp16 MFMA ----------------
__global__ __launch_bounds__(256, 2) void k_gemm_mfma(
    const _Float16* __restrict__ w_h, const float* __restrict__ s,
    const float* __restrict__ gat_w, const float* __restrict__ gat_b,
    float* __restrict__ G2) {
    __shared__ __align__(16) _Float16 Bs[2][128 * 64];  // [buf][g][k] swizzled image
    __shared__ float s_lds[2][2][128];                  // [buf][node][bs_local]

    int tid = threadIdx.x;
    int lane = tid & 63;
    int w = tid >> 6;
    int wm = w >> 1, wn = w & 1;
    int bm = blockIdx.x, bn = blockIdx.y, ks = blockIdx.z;
    int bs0 = bm * 128, g0 = bn * 128;
    int step0 = (ks * 250) >> 3;
    int nst = (((ks + 1) * 250) >> 3) - step0;  // 31 or 32

    int fbase = (lane >> 4) * 8;
    float w8[8], b8[8];
#pragma unroll
    for (int j = 0; j < 8; ++j) {
        w8[j] = gat_w[fbase + j];
        b8[j] = gat_b[fbase + j];
    }

    f32x4 acc[4][4] = {};

    auto stageB = [&](int buf, int stepg) {
#pragma unroll
        for (int qq = 0; qq < 4; ++qq) {
            int q = w * 4 + qq;
            int row_local = q * 8 + (lane >> 3);
            int sl = lane & 7;
            const _Float16* srcp = w_h + (size_t)(g0 + row_local) * KK + stepg * 64 + sl * 8;
            gload_lds16(srcp, &Bs[buf][q * 512]);
        }
        int row = tid >> 7, col = tid & 127;
        int n = 2 * stepg + row;
        s_lds[buf][row][col] = s[n * BS + bs0 + col];
    };

    auto compute = [&](int buf) {
#pragma unroll
        for (int kh = 0; kh < 2; ++kh) {
            f16x8 bfrag[4];
#pragma unroll
            for (int fn = 0; fn < 4; ++fn) {
                int grow = wn * 64 + fn * 16 + (lane & 15);
                int c = kh * 4 + (lane >> 4);
                int slot = c ^ (grow & 7);
                bfrag[fn] = *(const f16x8*)&Bs[buf][grow * 64 + slot * 8];
            }
#pragma unroll
            for (int fm = 0; fm < 4; ++fm) {
                float sval = s_lds[buf][kh][wm * 64 + fm * 16 + (lane & 15)];
                union { f16x8 v; __half2 h2[4]; } af;
#pragma unroll
                for (int j2 = 0; j2 < 4; ++j2) {
                    float t0 = fmaf(sval, w8[2 * j2], b8[2 * j2]);
                    float t1 = fmaf(sval, w8[2 * j2 + 1], b8[2 * j2 + 1]);
                    t0 = t0 > 0.f ? t0 : 0.f;
                    t1 = t1 > 0.f ? t1 : 0.f;
                    af.h2[j2] = __floats2half2_rn(t0, t1);
                }
#pragma unroll
                for (int fn = 0; fn < 4; ++fn) {
                    acc[fm][fn] =
                        __builtin_amdgcn_mfma_f32_16x16x32_f16(af.v, bfrag[fn], acc[fm][fn], 0, 0, 0);
                }
            }
        }
    };

    stageB(0, step0);
    __syncthreads();
    for (int t = 0; t < nst; ++t) {
        if (t + 1 < nst) stageB((t + 1) & 1, step0 + t + 1);
        compute(t & 1);
        __syncthreads();
    }

    float* Gks = G2 + (size_t)ks * BS * GG;
#pragma unroll
    for (int fm = 0; fm < 4; ++fm) {
#pragma unroll
        for (int fn = 0; fn < 4; ++fn) {
            int bs = bs0 + wm * 64 + fm * 16 + ((lane >> 4) << 2);
            int g = g0 + wn * 64 + fn * 16 + (lane & 15);
            float* base = Gks + (size_t)bs * GG + g;
#pragma unroll
            for (int r = 0; r < 4; ++r) base[r * GG] = acc[fm][fn][r];
        }
    }
}

// ---------------- reduce K-split partials + biases -> Xg[bs][512] ----------------
__global__ __launch_bounds__(256) void k_reduce(const float* __restrict__ G2,
                                                const float* __restrict__ b_ih,
                                                const float* __restrict__ b_hh,
                                                float* __restrict__ Xg) {
    int idx = blockIdx.x * 256 + threadIdx.x;  // 131072 float4 slots
    int e = idx * 4;
    int g = e & (GG - 1);
    float4 acc = *(const float4*)&b_ih[g];
    float4 bh = *(const float4*)&b_hh[g];
    acc.x += bh.x; acc.y += bh.y; acc.z += bh.z; acc.w += bh.w;
#pragma unroll
    for (int p = 0; p < KS; ++p) {
        float4 v = *(const float4*)&G2[(size_t)p * BS * GG + e];
        acc.x += v.x; acc.y += v.y; acc.z += v.z; acc.w += v.w;
    }
    *(float4*)&Xg[e] = acc;
}

// ---------------- LSTM: 16 blocks, 512 thr, quad-DPP reduce (r13, 47.6 us) ----------------
// Thread (d = tid>>2, kc = tid&3) owns gates {i,f,g,o} of hidden dim d over
// K-chunk [kc*32, +32). Accepted plateau: weights refetch from L2 per step
// (allocator demotes at any footprint: r10-r17 measured 7 alternatives, all
// slower). Quad-DPP butterfly; one lds_barrier/step; double-buffered h.
__global__ __launch_bounds__(512, 1) void k_lstm_shfl(const float* __restrict__ Xg,
                                                      const _Float16* __restrict__ whh_h,
                                                      const float* __restrict__ head_w,
                                                      const float* __restrict__ head_b,
                                                      float* __restrict__ out) {
    __shared__ __align__(16) _Float16 hb0[HH];
    __shared__ __align__(16) _Float16 hb1[HH];
    __shared__ __align__(16) float hf[HH];

    int tid = threadIdx.x;
    int b = blockIdx.x;
    int d = tid >> 2;   // 0..127
    int kc = tid & 3;   // 0..3
    int k0 = kc * 32;

    union U8 { f16x8 v; f16x2 h[4]; };

    // weights: w8[q][j] = Whh[q*128+d][k0 + j*8 .. +7]
    U8 w8[4][4];
#pragma unroll
    for (int q = 0; q < 4; ++q)
#pragma unroll
        for (int j = 0; j < 4; ++j)
            w8[q][j].v = *(const f16x8*)&whh_h[(q * HH + d) * HH + k0 + j * 8];
#pragma unroll
    for (int q = 0; q < 4; ++q)
#pragma unroll
        for (int j = 0; j < 4; ++j)
            asm volatile("" : "+v"(w8[q][j].v));

    if (tid < HH) hb0[tid] = (_Float16)0.f;
    float c = 0.f;
    float xg[4];
#pragma unroll
    for (int q = 0; q < 4; ++q) xg[q] = Xg[(size_t)(b * SS) * GG + q * HH + d];
    __syncthreads();

    auto lstm_step = [&](const _Float16* hr, _Float16* hw, int t) {
        U8 hh[4];
#pragma unroll
        for (int j = 0; j < 4; ++j) hh[j].v = *(const f16x8*)&hr[k0 + j * 8];
        float acc[4] = {0.f, 0.f, 0.f, 0.f};
#pragma unroll
        for (int j = 0; j < 4; ++j)
#pragma unroll
            for (int p = 0; p < 4; ++p) {
#pragma unroll
                for (int q = 0; q < 4; ++q)
                    acc[q] = fdot2(hh[j].h[p], w8[q][j].h[p], acc[q]);
            }
#pragma unroll
        for (int q = 0; q < 4; ++q) {
            acc[q] = dpp_add<0xB1>(acc[q]);  // quad_perm xor 1
            acc[q] = dpp_add<0x4E>(acc[q]);  // quad_perm xor 2
        }
        float ig = acc[0] + xg[0];
        float fg = acc[1] + xg[1];
        float gg = acc[2] + xg[2];
        float og = acc[3] + xg[3];
        int tn = (t + 1) & 63;
#pragma unroll
        for (int q = 0; q < 4; ++q)
            xg[q] = Xg[(size_t)(b * SS + tn) * GG + q * HH + d];
        float sf = fast_sigmoid(fg);
        float u = __expf(-ig);
        float wv = __expf(-2.f * fabsf(gg));
        float st = copysignf((1.f - wv) * __builtin_amdgcn_rcpf((1.f + u) * (1.f + wv)), gg);
        c = sf * c + st;
        float u2 = __expf(-og);
        float w2 = __expf(-2.f * fabsf(c));
        float h = copysignf((1.f - w2) * __builtin_amdgcn_rcpf((1.f + u2) * (1.f + w2)), c);
        if (kc == 0) {
            hw[d] = (_Float16)h;
            if (t == SS - 1) hf[d] = h;
        }
        lds_barrier();
    };

    for (int tt = 0; tt < SS; tt += 2) {
        lstm_step(hb0, hb1, tt);
        lstm_step(hb1, hb0, tt + 1);
    }

    __syncthreads();
    if (tid < NN) {
        float a0 = head_b[tid], a1 = 0.f, a2 = 0.f, a3 = 0.f;
        const float4* w4 = (const float4*)&head_w[tid * HH];
        const float4* h4 = (const float4*)hf;
#pragma unroll
        for (int j4 = 0; j4 < 32; ++j4) {
            float4 wv = w4[j4];
            float4 hv = h4[j4];
            a0 = fmaf(wv.x, hv.x, a0);
            a1 = fmaf(wv.y, hv.y, a1);
            a2 = fmaf(wv.z, hv.z, a2);
            a3 = fmaf(wv.w, hv.w, a3);
        }
        out[b * NN + tid] = (a0 + a1) + (a2 + a3);
    }
}

// ---------------- launch ----------------
extern "C" void kernel_launch(void* const* d_in, const int* in_sizes, int n_in, void* d_out,
                              int out_size, void* d_ws, size_t ws_size, hipStream_t stream) {
    const float* x = (const float*)d_in[0];
    const int* ei = (const int*)d_in[1];  // integer inputs arrive as int32
    const float* gat_w = (const float*)d_in[2];
    const float* a_src = (const float*)d_in[3];
    const float* a_dst = (const float*)d_in[4];
    const float* gat_b = (const float*)d_in[5];
    const float* w_ih = (const float*)d_in[6];
    const float* w_hh = (const float*)d_in[7];
    const float* b_ih = (const float*)d_in[8];
    const float* b_hh = (const float*)d_in[9];
    const float* head_w = (const float*)d_in[10];
    const float* head_b = (const float*)d_in[11];
    float* out = (float*)d_out;

    char* ws = (char*)d_ws;
    float* xt = (float*)(ws + 0);                      // 2,048,000 (dead after k_gat)
    float* s = (float*)(ws + 2048000u);                // 2,048,000 (dead after k_gemm)
    float* G2 = (float*)(ws + 4096000u);               // 8*1024*512*4 = 16,777,216
    _Float16* whh_h = (_Float16*)(ws + 37650432u);     // 131,072
    _Float16* w_h = (_Float16*)(ws + 37912576u);       // 16,384,000
    char* base2 = ws + 54296576u;                      // misc 65,536
    int* offsets = (int*)(base2);
    int* esrc = (int*)(base2 + 4096);
    float* scal = (float*)(base2 + 45056);
    float* Xg = (float*)(ws + 0);                      // 2,097,152 [bs][512] — overlaps xt+s
                                                       // (both dead by k_reduce; stream-ordered)

    k_prep<<<4864, 256, 0, stream>>>(x, xt, w_hh, whh_h, w_ih, w_h);
    k_graph<<<1, 512, 0, stream>>>(ei, gat_w, a_src, a_dst, offsets, esrc, scal);
    k_gat<<<NN, 256, 0, stream>>>(xt, offsets, esrc, scal, s);
    k_gemm_mfma<<<dim3(8, 4, KS), 256, 0, stream>>>(w_h, s, gat_w, gat_b, G2);
    k_reduce<<<512, 256, 0, stream>>>(G2, b_ih, b_hh, Xg);
    k_lstm_shfl<<<NB, 512, 0, stream>>>(Xg, whh_h, head_w, head_b, out);
}

// Round 19
// 122.470 us; speedup vs baseline: 1.1569x; 1.1200x over previous
//
#include <hip/hip_runtime.h>
#include <hip/hip_bf16.h>
#include <hip/hip_fp16.h>

// ---------------- problem constants ----------------
constexpr int NB = 16;       // batch
constexpr int SS = 64;       // seq len
constexpr int BS = 1024;     // NB*SS
constexpr int NN = 500;      // nodes
constexpr int FF = 32;       // gat out features
constexpr int EE = 8000;     // edges (without self loops)
constexpr int ET = 8500;     // edges + self loops
constexpr int KK = 16000;    // NN*FF  (lstm input size)
constexpr int HH = 128;      // lstm hidden
constexpr int GG = 512;      // 4*HH
constexpr int KS = 16;       // K-split for the big GEMM (250 steps of 64k)

typedef __attribute__((ext_vector_type(8))) _Float16 f16x8;
typedef __attribute__((ext_vector_type(2))) _Float16 f16x2;
typedef __attribute__((ext_vector_type(4))) float f32x4;

__device__ __forceinline__ void gload_lds16(const void* g, void* l) {
    __builtin_amdgcn_global_load_lds((const __attribute__((address_space(1))) void*)g,
                                     (__attribute__((address_space(3))) void*)l, 16, 0, 0);
}

__device__ __forceinline__ float fast_sigmoid(float x) {
    return __builtin_amdgcn_rcpf(1.f + __expf(-x));
}

__device__ __forceinline__ float fdot2(f16x2 a, f16x2 b, float c) {
#if __has_builtin(__builtin_amdgcn_fdot2)
    return __builtin_amdgcn_fdot2(a, b, c, false);
#else
    float r;
    asm("v_dot2_f32_f16 %0, %1, %2, %3" : "=v"(r) : "v"(a), "v"(b), "v"(c));
    return r;
#endif
}

// quad-lane butterfly add via DPP (full-rate VALU, no LDS). CTRL is an ICE.
template <int CTRL>
__device__ __forceinline__ float dpp_add(float x) {
    int y = __builtin_amdgcn_mov_dpp(__float_as_int(x), CTRL, 0xF, 0xF, true);
    return x + __int_as_float(y);
}

// LDS-only barrier: no memory clobber -> no vmcnt(0) drain; sched_barrier(0)
// pins ordering (guide rule #18).
__device__ __forceinline__ void lds_barrier() {
    __builtin_amdgcn_sched_barrier(0);
    asm volatile("s_waitcnt lgkmcnt(0)");
    __builtin_amdgcn_sched_barrier(0);
    __builtin_amdgcn_s_barrier();
    __builtin_amdgcn_sched_barrier(0);
}

// ---------------- fused prep: transpose_x | whh->fp16 | w_ih->fp16 swizzled | graph ----------------
// 512 threads. bid<512: x transpose. bid<640: whh cast. bid<2688: w_ih cast+swizzle.
// bid==2688: graph build (count->scan->scatter), overlapped with the bulk prep.
__global__ __launch_bounds__(512) void k_prep(const float* __restrict__ x, float* __restrict__ xt,
                                              const float* __restrict__ whh,
                                              _Float16* __restrict__ whh_h,
                                              const float* __restrict__ w_ih,
                                              _Float16* __restrict__ w_h,
                                              const int* __restrict__ ei,
                                              const float* __restrict__ gat_w,
                                              const float* __restrict__ a_src,
                                              const float* __restrict__ a_dst,
                                              int* __restrict__ offsets,
                                              int* __restrict__ esrc,
                                              float* __restrict__ scal) {
    int bid = blockIdx.x;
    int tid = threadIdx.x;
    if (bid < 512) {
        // xt[n][bs] = x[bs][n]
        __shared__ float tile[32][33];
        int n0 = (bid & 15) * 32, bs0 = (bid >> 4) * 32;
        int tx = tid & 31, ty = tid >> 5;  // 32 x 16
#pragma unroll
        for (int i = 0; i < 2; ++i) {
            int n = n0 + tx, bs = bs0 + ty + i * 16;
            tile[ty + i * 16][tx] = (n < NN) ? x[bs * NN + n] : 0.f;
        }
        __syncthreads();
#pragma unroll
        for (int i = 0; i < 2; ++i) {
            int n = n0 + ty + i * 16, bs = bs0 + tx;
            if (n < NN) xt[n * BS + bs] = tile[tx][ty + i * 16];
        }
    } else if (bid < 640) {
        // whh [512][128] fp32 -> fp16 (same layout); 128 blocks x 512
        int idx = (bid - 512) * 512 + tid;  // 65536
        whh_h[idx] = (_Float16)whh[idx];
    } else if (bid < 2688) {
        // w_h[g][blk*64 + sl*8 + j] = (fp16) w_ih[g][blk*64 + (sl^(g&7))*8 + j]
        int r = bid - 640;            // 0..2047
        int g = r >> 2;               // 512 rows
        int id = (r & 3) * 512 + tid; // 0..2047, 2000 used
        if (id < 2000) {
            int blk = id >> 3, sl = id & 7;
            int srcc = sl ^ (g & 7);
            const float* src = w_ih + (size_t)g * KK + blk * 64 + srcc * 8;
            float4 v0 = *(const float4*)src;
            float4 v1 = *(const float4*)(src + 4);
            union { __half2 h2[4]; uint4 q; } u;
            u.h2[0] = __floats2half2_rn(v0.x, v0.y);
            u.h2[1] = __floats2half2_rn(v0.z, v0.w);
            u.h2[2] = __floats2half2_rn(v1.x, v1.y);
            u.h2[3] = __floats2half2_rn(v1.z, v1.w);
            *(uint4*)(w_h + (size_t)g * KK + blk * 64 + sl * 8) = u.q;
        }
    } else {
        // graph build: count -> scan -> scatter (one 512-thread block)
        __shared__ int cnt[512];
        __shared__ int sc[2][512];
        __shared__ int cur[512];
        int t = tid;
        cnt[t] = 0;
        __syncthreads();
        for (int e = t; e < ET; e += 512) {
            int d = (e < EE) ? ei[EE + e] : (e - EE);
            atomicAdd(&cnt[d], 1);
        }
        __syncthreads();
        sc[0][t] = cnt[t];
        __syncthreads();
        int pb = 0;
        for (int off = 1; off < 512; off <<= 1) {
            int v = sc[pb][t];
            if (t >= off) v += sc[pb][t - off];
            sc[pb ^ 1][t] = v;
            pb ^= 1;
            __syncthreads();
        }
        int excl = sc[pb][t] - cnt[t];
        if (t <= NN) offsets[t] = excl;
        cur[t] = excl;
        if (t == 0) {
            float ws = 0.f, wd = 0.f;
            for (int f = 0; f < FF; ++f) {
                ws += gat_w[f] * a_src[f];
                wd += gat_w[f] * a_dst[f];
            }
            scal[0] = ws;
            scal[1] = wd;
        }
        __syncthreads();
        for (int e = t; e < ET; e += 512) {
            int sidx = (e < EE) ? ei[e] : (e - EE);
            int d = (e < EE) ? ei[EE + e] : (e - EE);
            int pos = atomicAdd(&cur[d], 1);
            esrc[pos] = sidx;
        }
    }
}

// ---------------- GAT: per-(n,bs) edge softmax -> s[n][bs] (r13 form) ----------------
__global__ void k_gat(const float* __restrict__ xt, const int* __restrict__ offsets,
                      const int* __restrict__ esrc, const float* __restrict__ scal,
                      float* __restrict__ s) {
    int n = blockIdx.y;
    int bs = blockIdx.x * 256 + threadIdx.x;
    float ws = scal[0], wd = scal[1];
    float xd = xt[n * BS + bs];
    float wdxd = wd * xd;
    int e0 = offsets[n], e1 = offsets[n + 1];
    float m = -1e30f, den = 0.f, num = 0.f;
    for (int j = e0; j < e1; ++j) {
        int sidx = esrc[j];  // uniform across wave
        float xs = xt[sidx * BS + bs];
        float z = ws * xs + wdxd;
        float l = (z > 0.f) ? z : 0.2f * z;  // leaky_relu 0.2
        if (l > m) {
            float r = __expf(m - l);
            den *= r;
            num *= r;
            m = l;
        }
        float p = __expf(l - m);
        den += p;
        num += p * xs;
    }
    s[n * BS + bs] = num / den;
}

// ---------------- big GEMM via fp16 MFMA (KS=16: 512 blocks = 2/CU) ----------------
__global__ __launch_bounds__(256, 2) void k_gemm_mfma(
    const _Float16* __restrict__ w_h, const float* __restrict__ s,
    const float* __restrict__ gat_w, const float* __restrict__ gat_b,
    float* __restrict__ G2) {
    __shared__ __align__(16) _Float16 Bs[2][128 * 64];  // [buf][g][k] swizzled image
    __shared__ float s_lds[2][2][128];                  // [buf][node][bs_local]

    int tid = threadIdx.x;
    int lane = tid & 63;
    int w = tid >> 6;
    int wm = w >> 1, wn = w & 1;
    int bm = blockIdx.x, bn = blockIdx.y, ks = blockIdx.z;
    int bs0 = bm * 128, g0 = bn * 128;
    int step0 = (ks * 250) >> 4;
    int nst = (((ks + 1) * 250) >> 4) - step0;  // 15 or 16

    int fbase = (lane >> 4) * 8;
    float w8[8], b8[8];
#pragma unroll
    for (int j = 0; j < 8; ++j) {
        w8[j] = gat_w[fbase + j];
        b8[j] = gat_b[fbase + j];
    }

    f32x4 acc[4][4] = {};

    auto stageB = [&](int buf, int stepg) {
#pragma unroll
        for (int qq = 0; qq < 4; ++qq) {
            int q = w * 4 + qq;
            int row_local = q * 8 + (lane >> 3);
            int sl = lane & 7;
            const _Float16* srcp = w_h + (size_t)(g0 + row_local) * KK + stepg * 64 + sl * 8;
            gload_lds16(srcp, &Bs[buf][q * 512]);
        }
        int row = tid >> 7, col = tid & 127;
        int n = 2 * stepg + row;
        s_lds[buf][row][col] = s[n * BS + bs0 + col];
    };

    auto compute = [&](int buf) {
#pragma unroll
        for (int kh = 0; kh < 2; ++kh) {
            f16x8 bfrag[4];
#pragma unroll
            for (int fn = 0; fn < 4; ++fn) {
                int grow = wn * 64 + fn * 16 + (lane & 15);
                int c = kh * 4 + (lane >> 4);
                int slot = c ^ (grow & 7);
                bfrag[fn] = *(const f16x8*)&Bs[buf][grow * 64 + slot * 8];
            }
#pragma unroll
            for (int fm = 0; fm < 4; ++fm) {
                float sval = s_lds[buf][kh][wm * 64 + fm * 16 + (lane & 15)];
                union { f16x8 v; __half2 h2[4]; } af;
#pragma unroll
                for (int j2 = 0; j2 < 4; ++j2) {
                    float t0 = fmaf(sval, w8[2 * j2], b8[2 * j2]);
                    float t1 = fmaf(sval, w8[2 * j2 + 1], b8[2 * j2 + 1]);
                    t0 = t0 > 0.f ? t0 : 0.f;
                    t1 = t1 > 0.f ? t1 : 0.f;
                    af.h2[j2] = __floats2half2_rn(t0, t1);
                }
#pragma unroll
                for (int fn = 0; fn < 4; ++fn) {
                    acc[fm][fn] =
                        __builtin_amdgcn_mfma_f32_16x16x32_f16(af.v, bfrag[fn], acc[fm][fn], 0, 0, 0);
                }
            }
        }
    };

    stageB(0, step0);
    __syncthreads();
    for (int t = 0; t < nst; ++t) {
        if (t + 1 < nst) stageB((t + 1) & 1, step0 + t + 1);
        compute(t & 1);
        __syncthreads();
    }

    float* Gks = G2 + (size_t)ks * BS * GG;
#pragma unroll
    for (int fm = 0; fm < 4; ++fm) {
#pragma unroll
        for (int fn = 0; fn < 4; ++fn) {
            int bs = bs0 + wm * 64 + fm * 16 + ((lane >> 4) << 2);
            int g = g0 + wn * 64 + fn * 16 + (lane & 15);
            float* base = Gks + (size_t)bs * GG + g;
#pragma unroll
            for (int r = 0; r < 4; ++r) base[r * GG] = acc[fm][fn][r];
        }
    }
}

// ---------------- reduce K-split partials + biases -> Xg[bs][512] ----------------
__global__ __launch_bounds__(256) void k_reduce(const float* __restrict__ G2,
                                                const float* __restrict__ b_ih,
                                                const float* __restrict__ b_hh,
                                                float* __restrict__ Xg) {
    int idx = blockIdx.x * 256 + threadIdx.x;  // 131072 float4 slots
    int e = idx * 4;
    int g = e & (GG - 1);
    float4 acc = *(const float4*)&b_ih[g];
    float4 bh = *(const float4*)&b_hh[g];
    acc.x += bh.x; acc.y += bh.y; acc.z += bh.z; acc.w += bh.w;
#pragma unroll
    for (int p = 0; p < KS; ++p) {
        float4 v = *(const float4*)&G2[(size_t)p * BS * GG + e];
        acc.x += v.x; acc.y += v.y; acc.z += v.z; acc.w += v.w;
    }
    *(float4*)&Xg[e] = acc;
}

// ---------------- LSTM: 16 blocks, 512 thr, quad-DPP reduce (r13, 47.6 us) ----------------
// Accepted plateau (r10-r17: 7 alternative weight-residency schemes all slower;
// weights refetch from L1/L2 each step). Quad-DPP butterfly; one lds_barrier/step.
__global__ __launch_bounds__(512, 1) void k_lstm_shfl(const float* __restrict__ Xg,
                                                      const _Float16* __restrict__ whh_h,
                                                      const float* __restrict__ head_w,
                                                      const float* __restrict__ head_b,
                                                      float* __restrict__ out) {
    __shared__ __align__(16) _Float16 hb0[HH];
    __shared__ __align__(16) _Float16 hb1[HH];
    __shared__ __align__(16) float hf[HH];

    int tid = threadIdx.x;
    int b = blockIdx.x;
    int d = tid >> 2;   // 0..127
    int kc = tid & 3;   // 0..3
    int k0 = kc * 32;

    union U8 { f16x8 v; f16x2 h[4]; };

    U8 w8[4][4];
#pragma unroll
    for (int q = 0; q < 4; ++q)
#pragma unroll
        for (int j = 0; j < 4; ++j)
            w8[q][j].v = *(const f16x8*)&whh_h[(q * HH + d) * HH + k0 + j * 8];
#pragma unroll
    for (int q = 0; q < 4; ++q)
#pragma unroll
        for (int j = 0; j < 4; ++j)
            asm volatile("" : "+v"(w8[q][j].v));

    if (tid < HH) hb0[tid] = (_Float16)0.f;
    float c = 0.f;
    float xg[4];
#pragma unroll
    for (int q = 0; q < 4; ++q) xg[q] = Xg[(size_t)(b * SS) * GG + q * HH + d];
    __syncthreads();

    auto lstm_step = [&](const _Float16* hr, _Float16* hw, int t) {
        U8 hh[4];
#pragma unroll
        for (int j = 0; j < 4; ++j) hh[j].v = *(const f16x8*)&hr[k0 + j * 8];
        float acc[4] = {0.f, 0.f, 0.f, 0.f};
#pragma unroll
        for (int j = 0; j < 4; ++j)
#pragma unroll
            for (int p = 0; p < 4; ++p) {
#pragma unroll
                for (int q = 0; q < 4; ++q)
                    acc[q] = fdot2(hh[j].h[p], w8[q][j].h[p], acc[q]);
            }
#pragma unroll
        for (int q = 0; q < 4; ++q) {
            acc[q] = dpp_add<0xB1>(acc[q]);  // quad_perm xor 1
            acc[q] = dpp_add<0x4E>(acc[q]);  // quad_perm xor 2
        }
        float ig = acc[0] + xg[0];
        float fg = acc[1] + xg[1];
        float gg = acc[2] + xg[2];
        float og = acc[3] + xg[3];
        int tn = (t + 1) & 63;
#pragma unroll
        for (int q = 0; q < 4; ++q)
            xg[q] = Xg[(size_t)(b * SS + tn) * GG + q * HH + d];
        float sf = fast_sigmoid(fg);
        float u = __expf(-ig);
        float wv = __expf(-2.f * fabsf(gg));
        float st = copysignf((1.f - wv) * __builtin_amdgcn_rcpf((1.f + u) * (1.f + wv)), gg);
        c = sf * c + st;
        float u2 = __expf(-og);
        float w2 = __expf(-2.f * fabsf(c));
        float h = copysignf((1.f - w2) * __builtin_amdgcn_rcpf((1.f + u2) * (1.f + w2)), c);
        if (kc == 0) {
            hw[d] = (_Float16)h;
            if (t == SS - 1) hf[d] = h;
        }
        lds_barrier();
    };

    for (int tt = 0; tt < SS; tt += 2) {
        lstm_step(hb0, hb1, tt);
        lstm_step(hb1, hb0, tt + 1);
    }

    __syncthreads();
    if (tid < NN) {
        float a0 = head_b[tid], a1 = 0.f, a2 = 0.f, a3 = 0.f;
        const float4* w4 = (const float4*)&head_w[tid * HH];
        const float4* h4 = (const float4*)hf;
#pragma unroll
        for (int j4 = 0; j4 < 32; ++j4) {
            float4 wv = w4[j4];
            float4 hv = h4[j4];
            a0 = fmaf(wv.x, hv.x, a0);
            a1 = fmaf(wv.y, hv.y, a1);
            a2 = fmaf(wv.z, hv.z, a2);
            a3 = fmaf(wv.w, hv.w, a3);
        }
        out[b * NN + tid] = (a0 + a1) + (a2 + a3);
    }
}

// ---------------- launch ----------------
extern "C" void kernel_launch(void* const* d_in, const int* in_sizes, int n_in, void* d_out,
                              int out_size, void* d_ws, size_t ws_size, hipStream_t stream) {
    const float* x = (const float*)d_in[0];
    const int* ei = (const int*)d_in[1];  // integer inputs arrive as int32
    const float* gat_w = (const float*)d_in[2];
    const float* a_src = (const float*)d_in[3];
    const float* a_dst = (const float*)d_in[4];
    const float* gat_b = (const float*)d_in[5];
    const float* w_ih = (const float*)d_in[6];
    const float* w_hh = (const float*)d_in[7];
    const float* b_ih = (const float*)d_in[8];
    const float* b_hh = (const float*)d_in[9];
    const float* head_w = (const float*)d_in[10];
    const float* head_b = (const float*)d_in[11];
    float* out = (float*)d_out;

    char* ws = (char*)d_ws;
    float* xt = (float*)(ws + 0);                      // 2,048,000 (dead after k_gat)
    float* s = (float*)(ws + 2048000u);                // 2,048,000 (dead after k_gemm)
    float* G2 = (float*)(ws + 4096000u);               // 16*1024*512*4 = 33,554,432
    _Float16* whh_h = (_Float16*)(ws + 37650432u);     // 131,072
    _Float16* w_h = (_Float16*)(ws + 37912576u);       // 16,384,000
    char* base2 = ws + 54296576u;                      // misc 65,536
    int* offsets = (int*)(base2);
    int* esrc = (int*)(base2 + 4096);
    float* scal = (float*)(base2 + 45056);
    float* Xg = (float*)(ws + 0);                      // 2,097,152 [bs][512] — overlaps xt+s
                                                       // (both dead by k_reduce; stream-ordered)

    k_prep<<<2689, 512, 0, stream>>>(x, xt, w_hh, whh_h, w_ih, w_h,
                                     ei, gat_w, a_src, a_dst, offsets, esrc, scal);
    k_gat<<<dim3(BS / 256, NN), 256, 0, stream>>>(xt, offsets, esrc, scal, s);
    k_gemm_mfma<<<dim3(8, 4, KS), 256, 0, stream>>>(w_h, s, gat_w, gat_b, G2);
    k_reduce<<<512, 256, 0, stream>>>(G2, b_ih, b_hh, Xg);
    k_lstm_shfl<<<NB, 512, 0, stream>>>(Xg, whh_h, head_w, head_b, out);
}

// Round 21
// 116.038 us; speedup vs baseline: 1.2210x; 1.0554x over previous
//
#include <hip/hip_runtime.h>
#include <hip/hip_bf16.h>
#include <hip/hip_fp16.h>

// ---------------- problem constants ----------------
constexpr int NB = 16;       // batch
constexpr int SS = 64;       // seq len
constexpr int BS = 1024;     // NB*SS
constexpr int NN = 500;      // nodes
constexpr int FF = 32;       // gat out features
constexpr int EE = 8000;     // edges (without self loops)
constexpr int ET = 8500;     // edges + self loops
constexpr int KK = 16000;    // NN*FF  (lstm input size)
constexpr int HH = 128;      // lstm hidden
constexpr int GG = 512;      // 4*HH
constexpr int KS = 16;       // K-split for the big GEMM

typedef __attribute__((ext_vector_type(8))) _Float16 f16x8;
typedef __attribute__((ext_vector_type(2))) _Float16 f16x2;
typedef __attribute__((ext_vector_type(4))) float f32x4;

__device__ __forceinline__ void gload_lds16(const void* g, void* l) {
    __builtin_amdgcn_global_load_lds((const __attribute__((address_space(1))) void*)g,
                                     (__attribute__((address_space(3))) void*)l, 16, 0, 0);
}

__device__ __forceinline__ float fast_sigmoid(float x) {
    return __builtin_amdgcn_rcpf(1.f + __expf(-x));
}

__device__ __forceinline__ float fdot2(f16x2 a, f16x2 b, float c) {
#if __has_builtin(__builtin_amdgcn_fdot2)
    return __builtin_amdgcn_fdot2(a, b, c, false);
#else
    float r;
    asm("v_dot2_f32_f16 %0, %1, %2, %3" : "=v"(r) : "v"(a), "v"(b), "v"(c));
    return r;
#endif
}

// quad-lane butterfly add via DPP (full-rate VALU, no LDS). CTRL is an ICE.
template <int CTRL>
__device__ __forceinline__ float dpp_add(float x) {
    int y = __builtin_amdgcn_mov_dpp(__float_as_int(x), CTRL, 0xF, 0xF, true);
    return x + __int_as_float(y);
}

// LDS-only barrier: no memory clobber -> no vmcnt(0) drain; sched_barrier(0)
// pins ordering (guide rule #18).
__device__ __forceinline__ void lds_barrier() {
    __builtin_amdgcn_sched_barrier(0);
    asm volatile("s_waitcnt lgkmcnt(0)");
    __builtin_amdgcn_sched_barrier(0);
    __builtin_amdgcn_s_barrier();
    __builtin_amdgcn_sched_barrier(0);
}

// ---------------- fused prep: transpose_x | whh->fp16 | w_ih->fp16 swizzled | graph ----------------
__global__ __launch_bounds__(512) void k_prep(const float* __restrict__ x, float* __restrict__ xt,
                                              const float* __restrict__ whh,
                                              _Float16* __restrict__ whh_h,
                                              const float* __restrict__ w_ih,
                                              _Float16* __restrict__ w_h,
                                              const int* __restrict__ ei,
                                              const float* __restrict__ gat_w,
                                              const float* __restrict__ a_src,
                                              const float* __restrict__ a_dst,
                                              int* __restrict__ offsets,
                                              int* __restrict__ esrc,
                                              float* __restrict__ scal) {
    int bid = blockIdx.x;
    int tid = threadIdx.x;
    if (bid < 512) {
        // xt[n][bs] = x[bs][n]
        __shared__ float tile[32][33];
        int n0 = (bid & 15) * 32, bs0 = (bid >> 4) * 32;
        int tx = tid & 31, ty = tid >> 5;  // 32 x 16
#pragma unroll
        for (int i = 0; i < 2; ++i) {
            int n = n0 + tx, bs = bs0 + ty + i * 16;
            tile[ty + i * 16][tx] = (n < NN) ? x[bs * NN + n] : 0.f;
        }
        __syncthreads();
#pragma unroll
        for (int i = 0; i < 2; ++i) {
            int n = n0 + ty + i * 16, bs = bs0 + tx;
            if (n < NN) xt[n * BS + bs] = tile[tx][ty + i * 16];
        }
    } else if (bid < 640) {
        int idx = (bid - 512) * 512 + tid;  // 65536
        whh_h[idx] = (_Float16)whh[idx];
    } else if (bid < 2688) {
        int r = bid - 640;            // 0..2047
        int g = r >> 2;               // 512 rows
        int id = (r & 3) * 512 + tid; // 0..2047, 2000 used
        if (id < 2000) {
            int blk = id >> 3, sl = id & 7;
            int srcc = sl ^ (g & 7);
            const float* src = w_ih + (size_t)g * KK + blk * 64 + srcc * 8;
            float4 v0 = *(const float4*)src;
            float4 v1 = *(const float4*)(src + 4);
            union { f16x2 h2[4]; uint4 q; } u;
            u.h2[0] = f16x2{(_Float16)v0.x, (_Float16)v0.y};
            u.h2[1] = f16x2{(_Float16)v0.z, (_Float16)v0.w};
            u.h2[2] = f16x2{(_Float16)v1.x, (_Float16)v1.y};
            u.h2[3] = f16x2{(_Float16)v1.z, (_Float16)v1.w};
            *(uint4*)(w_h + (size_t)g * KK + blk * 64 + sl * 8) = u.q;
        }
    } else {
        // graph build: count -> scan -> scatter (one 512-thread block)
        __shared__ int cnt[512];
        __shared__ int sc[2][512];
        __shared__ int cur[512];
        int t = tid;
        cnt[t] = 0;
        __syncthreads();
        for (int e = t; e < ET; e += 512) {
            int d = (e < EE) ? ei[EE + e] : (e - EE);
            atomicAdd(&cnt[d], 1);
        }
        __syncthreads();
        sc[0][t] = cnt[t];
        __syncthreads();
        int pb = 0;
        for (int off = 1; off < 512; off <<= 1) {
            int v = sc[pb][t];
            if (t >= off) v += sc[pb][t - off];
            sc[pb ^ 1][t] = v;
            pb ^= 1;
            __syncthreads();
        }
        int excl = sc[pb][t] - cnt[t];
        if (t <= NN) offsets[t] = excl;
        cur[t] = excl;
        if (t == 0) {
            float ws = 0.f, wd = 0.f;
            for (int f = 0; f < FF; ++f) {
                ws += gat_w[f] * a_src[f];
                wd += gat_w[f] * a_dst[f];
            }
            scal[0] = ws;
            scal[1] = wd;
        }
        __syncthreads();
        for (int e = t; e < ET; e += 512) {
            int sidx = (e < EE) ? ei[e] : (e - EE);
            int d = (e < EE) ? ei[EE + e] : (e - EE);
            int pos = atomicAdd(&cur[d], 1);
            esrc[pos] = sidx;
        }
    }
}

// ---------------- GAT: per-(n,bs) edge softmax -> s[n][bs] ----------------
__global__ void k_gat(const float* __restrict__ xt, const int* __restrict__ offsets,
                      const int* __restrict__ esrc, const float* __restrict__ scal,
                      float* __restrict__ s) {
    int n = blockIdx.y;
    int bs = blockIdx.x * 256 + threadIdx.x;
    float ws = scal[0], wd = scal[1];
    float xd = xt[n * BS + bs];
    float wdxd = wd * xd;
    int e0 = offsets[n], e1 = offsets[n + 1];
    float m = -1e30f, den = 0.f, num = 0.f;
    for (int j = e0; j < e1; ++j) {
        int sidx = esrc[j];  // uniform across wave
        float xs = xt[sidx * BS + bs];
        float z = ws * xs + wdxd;
        float l = (z > 0.f) ? z : 0.2f * z;  // leaky_relu 0.2
        if (l > m) {
            float r = __expf(m - l);
            den *= r;
            num *= r;
            m = l;
        }
        float p = __expf(l - m);
        den += p;
        num += p * xs;
    }
    s[n * BS + bs] = num / den;
}

// ---------------- big GEMM via fp16 MFMA ----------------
// grid (x=ks, y=bn, z=bm): the 8 bm-siblings sharing a B panel are 64 apart in
// linear block id -> 64%8==0 -> same XCD -> B panel L2-hits after first fetch.
// A-build in packed fp16 (native vector ops -> v_pk_fma_f16 / v_pk_max_f16).
__global__ __launch_bounds__(256, 2) void k_gemm_mfma(
    const _Float16* __restrict__ w_h, const float* __restrict__ s,
    const float* __restrict__ gat_w, const float* __restrict__ gat_b,
    float* __restrict__ G2) {
    __shared__ __align__(16) _Float16 Bs[2][128 * 64];  // [buf][g][k] swizzled image
    __shared__ float s_lds[2][2][128];                  // [buf][node][bs_local]

    int tid = threadIdx.x;
    int lane = tid & 63;
    int w = tid >> 6;
    int wm = w >> 1, wn = w & 1;
    int ks = blockIdx.x, bn = blockIdx.y, bm = blockIdx.z;
    int bs0 = bm * 128, g0 = bn * 128;
    int step0 = (ks * 250) >> 4;
    int nst = (((ks + 1) * 250) >> 4) - step0;  // 15 or 16

    // per-lane gat affine params, packed fp16 (k-slots f = fbase + 2*j2 + {0,1})
    int fbase = (lane >> 4) * 8;
    f16x2 wv2[4], bv2[4];
#pragma unroll
    for (int j2 = 0; j2 < 4; ++j2) {
        wv2[j2] = f16x2{(_Float16)gat_w[fbase + 2 * j2], (_Float16)gat_w[fbase + 2 * j2 + 1]};
        bv2[j2] = f16x2{(_Float16)gat_b[fbase + 2 * j2], (_Float16)gat_b[fbase + 2 * j2 + 1]};
    }
    const f16x2 zero2 = {(_Float16)0.f, (_Float16)0.f};

    f32x4 acc[4][4] = {};

    auto stageB = [&](int buf, int stepg) {
#pragma unroll
        for (int qq = 0; qq < 4; ++qq) {
            int q = w * 4 + qq;
            int row_local = q * 8 + (lane >> 3);
            int sl = lane & 7;
            const _Float16* srcp = w_h + (size_t)(g0 + row_local) * KK + stepg * 64 + sl * 8;
            gload_lds16(srcp, &Bs[buf][q * 512]);
        }
        int row = tid >> 7, col = tid & 127;
        int n = 2 * stepg + row;
        s_lds[buf][row][col] = s[n * BS + bs0 + col];
    };

    auto compute = [&](int buf) {
#pragma unroll
        for (int kh = 0; kh < 2; ++kh) {
            f16x8 bfrag[4];
#pragma unroll
            for (int fn = 0; fn < 4; ++fn) {
                int grow = wn * 64 + fn * 16 + (lane & 15);
                int c = kh * 4 + (lane >> 4);
                int slot = c ^ (grow & 7);
                bfrag[fn] = *(const f16x8*)&Bs[buf][grow * 64 + slot * 8];
            }
#pragma unroll
            for (int fm = 0; fm < 4; ++fm) {
                float sval = s_lds[buf][kh][wm * 64 + fm * 16 + (lane & 15)];
                _Float16 sh = (_Float16)sval;
                f16x2 s2 = {sh, sh};
                union { f16x8 v; f16x2 h2[4]; } af;
#pragma unroll
                for (int j2 = 0; j2 < 4; ++j2) {
                    f16x2 t = s2 * wv2[j2] + bv2[j2];
                    af.h2[j2] = __builtin_elementwise_max(t, zero2);
                }
#pragma unroll
                for (int fn = 0; fn < 4; ++fn) {
                    acc[fm][fn] =
                        __builtin_amdgcn_mfma_f32_16x16x32_f16(af.v, bfrag[fn], acc[fm][fn], 0, 0, 0);
                }
            }
        }
    };

    stageB(0, step0);
    __syncthreads();
    for (int t = 0; t < nst; ++t) {
        if (t + 1 < nst) stageB((t + 1) & 1, step0 + t + 1);
        compute(t & 1);
        __syncthreads();
    }

    float* Gks = G2 + (size_t)ks * BS * GG;
#pragma unroll
    for (int fm = 0; fm < 4; ++fm) {
#pragma unroll
        for (int fn = 0; fn < 4; ++fn) {
            int bs = bs0 + wm * 64 + fm * 16 + ((lane >> 4) << 2);
            int g = g0 + wn * 64 + fn * 16 + (lane & 15);
            float* base = Gks + (size_t)bs * GG + g;
#pragma unroll
            for (int r = 0; r < 4; ++r) base[r * GG] = acc[fm][fn][r];
        }
    }
}

// ---------------- reduce K-split partials + biases -> Xg[bs][512] ----------------
__global__ __launch_bounds__(256) void k_reduce(const float* __restrict__ G2,
                                                const float* __restrict__ b_ih,
                                                const float* __restrict__ b_hh,
                                                float* __restrict__ Xg) {
    int idx = blockIdx.x * 256 + threadIdx.x;  // 131072 float4 slots
    int e = idx * 4;
    int g = e & (GG - 1);
    float4 acc = *(const float4*)&b_ih[g];
    float4 bh = *(const float4*)&b_hh[g];
    acc.x += bh.x; acc.y += bh.y; acc.z += bh.z; acc.w += bh.w;
#pragma unroll
    for (int p = 0; p < KS; ++p) {
        float4 v = *(const float4*)&G2[(size_t)p * BS * GG + e];
        acc.x += v.x; acc.y += v.y; acc.z += v.z; acc.w += v.w;
    }
    *(float4*)&Xg[e] = acc;
}

// ---------------- LSTM: 16 blocks, 512 thr, quad-DPP reduce (r13, 47.6 us) ----------------
__global__ __launch_bounds__(512, 1) void k_lstm_shfl(const float* __restrict__ Xg,
                                                      const _Float16* __restrict__ whh_h,
                                                      const float* __restrict__ head_w,
                                                      const float* __restrict__ head_b,
                                                      float* __restrict__ out) {
    __shared__ __align__(16) _Float16 hb0[HH];
    __shared__ __align__(16) _Float16 hb1[HH];
    __shared__ __align__(16) float hf[HH];

    int tid = threadIdx.x;
    int b = blockIdx.x;
    int d = tid >> 2;   // 0..127
    int kc = tid & 3;   // 0..3
    int k0 = kc * 32;

    union U8 { f16x8 v; f16x2 h[4]; };

    U8 w8[4][4];
#pragma unroll
    for (int q = 0; q < 4; ++q)
#pragma unroll
        for (int j = 0; j < 4; ++j)
            w8[q][j].v = *(const f16x8*)&whh_h[(q * HH + d) * HH + k0 + j * 8];
#pragma unroll
    for (int q = 0; q < 4; ++q)
#pragma unroll
        for (int j = 0; j < 4; ++j)
            asm volatile("" : "+v"(w8[q][j].v));

    if (tid < HH) hb0[tid] = (_Float16)0.f;
    float c = 0.f;
    float xg[4];
#pragma unroll
    for (int q = 0; q < 4; ++q) xg[q] = Xg[(size_t)(b * SS) * GG + q * HH + d];
    __syncthreads();

    auto lstm_step = [&](const _Float16* hr, _Float16* hw, int t) {
        U8 hh[4];
#pragma unroll
        for (int j = 0; j < 4; ++j) hh[j].v = *(const f16x8*)&hr[k0 + j * 8];
        float acc[4] = {0.f, 0.f, 0.f, 0.f};
#pragma unroll
        for (int j = 0; j < 4; ++j)
#pragma unroll
            for (int p = 0; p < 4; ++p) {
#pragma unroll
                for (int q = 0; q < 4; ++q)
                    acc[q] = fdot2(hh[j].h[p], w8[q][j].h[p], acc[q]);
            }
#pragma unroll
        for (int q = 0; q < 4; ++q) {
            acc[q] = dpp_add<0xB1>(acc[q]);  // quad_perm xor 1
            acc[q] = dpp_add<0x4E>(acc[q]);  // quad_perm xor 2
        }
        float ig = acc[0] + xg[0];
        float fg = acc[1] + xg[1];
        float gg = acc[2] + xg[2];
        float og = acc[3] + xg[3];
        int tn = (t + 1) & 63;
#pragma unroll
        for (int q = 0; q < 4; ++q)
            xg[q] = Xg[(size_t)(b * SS + tn) * GG + q * HH + d];
        float sf = fast_sigmoid(fg);
        float u = __expf(-ig);
        float wv = __expf(-2.f * fabsf(gg));
        float st = copysignf((1.f - wv) * __builtin_amdgcn_rcpf((1.f + u) * (1.f + wv)), gg);
        c = sf * c + st;
        float u2 = __expf(-og);
        float w2 = __expf(-2.f * fabsf(c));
        float h = copysignf((1.f - w2) * __builtin_amdgcn_rcpf((1.f + u2) * (1.f + w2)), c);
        if (kc == 0) {
            hw[d] = (_Float16)h;
            if (t == SS - 1) hf[d] = h;
        }
        lds_barrier();
    };

    for (int tt = 0; tt < SS; tt += 2) {
        lstm_step(hb0, hb1, tt);
        lstm_step(hb1, hb0, tt + 1);
    }

    __syncthreads();
    if (tid < NN) {
        float a0 = head_b[tid], a1 = 0.f, a2 = 0.f, a3 = 0.f;
        const float4* w4 = (const float4*)&head_w[tid * HH];
        const float4* h4 = (const float4*)hf;
#pragma unroll
        for (int j4 = 0; j4 < 32; ++j4) {
            float4 wv = w4[j4];
            float4 hv = h4[j4];
            a0 = fmaf(wv.x, hv.x, a0);
            a1 = fmaf(wv.y, hv.y, a1);
            a2 = fmaf(wv.z, hv.z, a2);
            a3 = fmaf(wv.w, hv.w, a3);
        }
        out[b * NN + tid] = (a0 + a1) + (a2 + a3);
    }
}

// ---------------- launch ----------------
extern "C" void kernel_launch(void* const* d_in, const int* in_sizes, int n_in, void* d_out,
                              int out_size, void* d_ws, size_t ws_size, hipStream_t stream) {
    const float* x = (const float*)d_in[0];
    const int* ei = (const int*)d_in[1];  // integer inputs arrive as int32
    const float* gat_w = (const float*)d_in[2];
    const float* a_src = (const float*)d_in[3];
    const float* a_dst = (const float*)d_in[4];
    const float* gat_b = (const float*)d_in[5];
    const float* w_ih = (const float*)d_in[6];
    const float* w_hh = (const float*)d_in[7];
    const float* b_ih = (const float*)d_in[8];
    const float* b_hh = (const float*)d_in[9];
    const float* head_w = (const float*)d_in[10];
    const float* head_b = (const float*)d_in[11];
    float* out = (float*)d_out;

    char* ws = (char*)d_ws;
    float* xt = (float*)(ws + 0);                      // 2,048,000 (dead after k_gat)
    float* s = (float*)(ws + 2048000u);                // 2,048,000 (dead after k_gemm)
    float* G2 = (float*)(ws + 4096000u);               // 16*1024*512*4 = 33,554,432
    _Float16* whh_h = (_Float16*)(ws + 37650432u);     // 131,072
    _Float16* w_h = (_Float16*)(ws + 37912576u);       // 16,384,000
    char* base2 = ws + 54296576u;                      // misc 65,536
    int* offsets = (int*)(base2);
    int* esrc = (int*)(base2 + 4096);
    float* scal = (float*)(base2 + 45056);
    float* Xg = (float*)(ws + 0);                      // 2,097,152 [bs][512] — overlaps xt+s
                                                       // (both dead by k_reduce; stream-ordered)

    k_prep<<<2689, 512, 0, stream>>>(x, xt, w_hh, whh_h, w_ih, w_h,
                                     ei, gat_w, a_src, a_dst, offsets, esrc, scal);
    k_gat<<<dim3(BS / 256, NN), 256, 0, stream>>>(xt, offsets, esrc, scal, s);
    k_gemm_mfma<<<dim3(KS, 4, 8), 256, 0, stream>>>(w_h, s, gat_w, gat_b, G2);
    k_reduce<<<512, 256, 0, stream>>>(G2, b_ih, b_hh, Xg);
    k_lstm_shfl<<<NB, 512, 0, stream>>>(Xg, whh_h, head_w, head_b, out);
}

// Round 22
// 113.556 us; speedup vs baseline: 1.2477x; 1.0219x over previous
//
#include <hip/hip_runtime.h>
#include <hip/hip_bf16.h>
#include <hip/hip_fp16.h>

// ---------------- problem constants ----------------
constexpr int NB = 16;       // batch
constexpr int SS = 64;       // seq len
constexpr int BS = 1024;     // NB*SS
constexpr int NN = 500;      // nodes
constexpr int FF = 32;       // gat out features
constexpr int EE = 8000;     // edges (without self loops)
constexpr int ET = 8500;     // edges + self loops
constexpr int KK = 16000;    // NN*FF  (lstm input size)
constexpr int HH = 128;      // lstm hidden
constexpr int GG = 512;      // 4*HH
constexpr int KS = 16;       // K-split for the big GEMM

typedef __attribute__((ext_vector_type(8))) _Float16 f16x8;
typedef __attribute__((ext_vector_type(2))) _Float16 f16x2;
typedef __attribute__((ext_vector_type(4))) float f32x4;

__device__ __forceinline__ void gload_lds16(const void* g, void* l) {
    __builtin_amdgcn_global_load_lds((const __attribute__((address_space(1))) void*)g,
                                     (__attribute__((address_space(3))) void*)l, 16, 0, 0);
}

__device__ __forceinline__ float fast_sigmoid(float x) {
    return __builtin_amdgcn_rcpf(1.f + __expf(-x));
}

__device__ __forceinline__ float fdot2(f16x2 a, f16x2 b, float c) {
#if __has_builtin(__builtin_amdgcn_fdot2)
    return __builtin_amdgcn_fdot2(a, b, c, false);
#else
    float r;
    asm("v_dot2_f32_f16 %0, %1, %2, %3" : "=v"(r) : "v"(a), "v"(b), "v"(c));
    return r;
#endif
}

// quad-lane butterfly add via DPP (full-rate VALU, no LDS). CTRL is an ICE.
template <int CTRL>
__device__ __forceinline__ float dpp_add(float x) {
    int y = __builtin_amdgcn_mov_dpp(__float_as_int(x), CTRL, 0xF, 0xF, true);
    return x + __int_as_float(y);
}

// LDS-only barrier: no memory clobber -> no vmcnt(0) drain; sched_barrier(0)
// pins ordering (guide rule #18).
__device__ __forceinline__ void lds_barrier() {
    __builtin_amdgcn_sched_barrier(0);
    asm volatile("s_waitcnt lgkmcnt(0)");
    __builtin_amdgcn_sched_barrier(0);
    __builtin_amdgcn_s_barrier();
    __builtin_amdgcn_sched_barrier(0);
}

// ---------------- fused prep: transpose_x | whh->fp16 | w_ih->fp16 swizzled | graph ----------------
__global__ __launch_bounds__(512) void k_prep(const float* __restrict__ x, float* __restrict__ xt,
                                              const float* __restrict__ whh,
                                              _Float16* __restrict__ whh_h,
                                              const float* __restrict__ w_ih,
                                              _Float16* __restrict__ w_h,
                                              const int* __restrict__ ei,
                                              const float* __restrict__ gat_w,
                                              const float* __restrict__ a_src,
                                              const float* __restrict__ a_dst,
                                              int* __restrict__ offsets,
                                              int* __restrict__ esrc,
                                              float* __restrict__ scal) {
    int bid = blockIdx.x;
    int tid = threadIdx.x;
    if (bid < 512) {
        // xt[n][bs] = x[bs][n]
        __shared__ float tile[32][33];
        int n0 = (bid & 15) * 32, bs0 = (bid >> 4) * 32;
        int tx = tid & 31, ty = tid >> 5;  // 32 x 16
#pragma unroll
        for (int i = 0; i < 2; ++i) {
            int n = n0 + tx, bs = bs0 + ty + i * 16;
            tile[ty + i * 16][tx] = (n < NN) ? x[bs * NN + n] : 0.f;
        }
        __syncthreads();
#pragma unroll
        for (int i = 0; i < 2; ++i) {
            int n = n0 + ty + i * 16, bs = bs0 + tx;
            if (n < NN) xt[n * BS + bs] = tile[tx][ty + i * 16];
        }
    } else if (bid < 640) {
        int idx = (bid - 512) * 512 + tid;  // 65536
        whh_h[idx] = (_Float16)whh[idx];
    } else if (bid < 2688) {
        int r = bid - 640;            // 0..2047
        int g = r >> 2;               // 512 rows
        int id = (r & 3) * 512 + tid; // 0..2047, 2000 used
        if (id < 2000) {
            int blk = id >> 3, sl = id & 7;
            int srcc = sl ^ (g & 7);
            const float* src = w_ih + (size_t)g * KK + blk * 64 + srcc * 8;
            float4 v0 = *(const float4*)src;
            float4 v1 = *(const float4*)(src + 4);
            union { f16x2 h2[4]; uint4 q; } u;
            u.h2[0] = f16x2{(_Float16)v0.x, (_Float16)v0.y};
            u.h2[1] = f16x2{(_Float16)v0.z, (_Float16)v0.w};
            u.h2[2] = f16x2{(_Float16)v1.x, (_Float16)v1.y};
            u.h2[3] = f16x2{(_Float16)v1.z, (_Float16)v1.w};
            *(uint4*)(w_h + (size_t)g * KK + blk * 64 + sl * 8) = u.q;
        }
    } else {
        // graph build: count -> scan -> scatter (one 512-thread block)
        __shared__ int cnt[512];
        __shared__ int sc[2][512];
        __shared__ int cur[512];
        int t = tid;
        cnt[t] = 0;
        __syncthreads();
        for (int e = t; e < ET; e += 512) {
            int d = (e < EE) ? ei[EE + e] : (e - EE);
            atomicAdd(&cnt[d], 1);
        }
        __syncthreads();
        sc[0][t] = cnt[t];
        __syncthreads();
        int pb = 0;
        for (int off = 1; off < 512; off <<= 1) {
            int v = sc[pb][t];
            if (t >= off) v += sc[pb][t - off];
            sc[pb ^ 1][t] = v;
            pb ^= 1;
            __syncthreads();
        }
        int excl = sc[pb][t] - cnt[t];
        if (t <= NN) offsets[t] = excl;
        cur[t] = excl;
        if (t == 0) {
            float ws = 0.f, wd = 0.f;
            for (int f = 0; f < FF; ++f) {
                ws += gat_w[f] * a_src[f];
                wd += gat_w[f] * a_dst[f];
            }
            scal[0] = ws;
            scal[1] = wd;
        }
        __syncthreads();
        for (int e = t; e < ET; e += 512) {
            int sidx = (e < EE) ? ei[e] : (e - EE);
            int d = (e < EE) ? ei[EE + e] : (e - EE);
            int pos = atomicAdd(&cur[d], 1);
            esrc[pos] = sidx;
        }
    }
}

// ---------------- GAT: per-(n,bs) edge softmax -> s[n][bs] ----------------
__global__ void k_gat(const float* __restrict__ xt, const int* __restrict__ offsets,
                      const int* __restrict__ esrc, const float* __restrict__ scal,
                      float* __restrict__ s) {
    int n = blockIdx.y;
    int bs = blockIdx.x * 256 + threadIdx.x;
    float ws = scal[0], wd = scal[1];
    float xd = xt[n * BS + bs];
    float wdxd = wd * xd;
    int e0 = offsets[n], e1 = offsets[n + 1];
    float m = -1e30f, den = 0.f, num = 0.f;
    for (int j = e0; j < e1; ++j) {
        int sidx = esrc[j];  // uniform across wave
        float xs = xt[sidx * BS + bs];
        float z = ws * xs + wdxd;
        float l = (z > 0.f) ? z : 0.2f * z;  // leaky_relu 0.2
        if (l > m) {
            float r = __expf(m - l);
            den *= r;
            num *= r;
            m = l;
        }
        float p = __expf(l - m);
        den += p;
        num += p * xs;
    }
    s[n * BS + bs] = num / den;
}

// ---------------- big GEMM via fp16 MFMA, fp16 partial output ----------------
// grid (x=ks, y=bn, z=bm): the 8 bm-siblings sharing a B panel are 64 apart in
// linear block id -> same XCD -> B panel L2-hits after first fetch.
// A-build in packed fp16. G2 partials stored fp16 (halves write + reduce read).
__global__ __launch_bounds__(256, 2) void k_gemm_mfma(
    const _Float16* __restrict__ w_h, const float* __restrict__ s,
    const float* __restrict__ gat_w, const float* __restrict__ gat_b,
    _Float16* __restrict__ G2h) {
    __shared__ __align__(16) _Float16 Bs[2][128 * 64];  // [buf][g][k] swizzled image
    __shared__ float s_lds[2][2][128];                  // [buf][node][bs_local]

    int tid = threadIdx.x;
    int lane = tid & 63;
    int w = tid >> 6;
    int wm = w >> 1, wn = w & 1;
    int ks = blockIdx.x, bn = blockIdx.y, bm = blockIdx.z;
    int bs0 = bm * 128, g0 = bn * 128;
    int step0 = (ks * 250) >> 4;
    int nst = (((ks + 1) * 250) >> 4) - step0;  // 15 or 16

    // per-lane gat affine params, packed fp16 (k-slots f = fbase + 2*j2 + {0,1})
    int fbase = (lane >> 4) * 8;
    f16x2 wv2[4], bv2[4];
#pragma unroll
    for (int j2 = 0; j2 < 4; ++j2) {
        wv2[j2] = f16x2{(_Float16)gat_w[fbase + 2 * j2], (_Float16)gat_w[fbase + 2 * j2 + 1]};
        bv2[j2] = f16x2{(_Float16)gat_b[fbase + 2 * j2], (_Float16)gat_b[fbase + 2 * j2 + 1]};
    }
    const f16x2 zero2 = {(_Float16)0.f, (_Float16)0.f};

    f32x4 acc[4][4] = {};

    auto stageB = [&](int buf, int stepg) {
#pragma unroll
        for (int qq = 0; qq < 4; ++qq) {
            int q = w * 4 + qq;
            int row_local = q * 8 + (lane >> 3);
            int sl = lane & 7;
            const _Float16* srcp = w_h + (size_t)(g0 + row_local) * KK + stepg * 64 + sl * 8;
            gload_lds16(srcp, &Bs[buf][q * 512]);
        }
        int row = tid >> 7, col = tid & 127;
        int n = 2 * stepg + row;
        s_lds[buf][row][col] = s[n * BS + bs0 + col];
    };

    auto compute = [&](int buf) {
#pragma unroll
        for (int kh = 0; kh < 2; ++kh) {
            f16x8 bfrag[4];
#pragma unroll
            for (int fn = 0; fn < 4; ++fn) {
                int grow = wn * 64 + fn * 16 + (lane & 15);
                int c = kh * 4 + (lane >> 4);
                int slot = c ^ (grow & 7);
                bfrag[fn] = *(const f16x8*)&Bs[buf][grow * 64 + slot * 8];
            }
#pragma unroll
            for (int fm = 0; fm < 4; ++fm) {
                float sval = s_lds[buf][kh][wm * 64 + fm * 16 + (lane & 15)];
                _Float16 sh = (_Float16)sval;
                f16x2 s2 = {sh, sh};
                union { f16x8 v; f16x2 h2[4]; } af;
#pragma unroll
                for (int j2 = 0; j2 < 4; ++j2) {
                    f16x2 t = s2 * wv2[j2] + bv2[j2];
                    af.h2[j2] = __builtin_elementwise_max(t, zero2);
                }
#pragma unroll
                for (int fn = 0; fn < 4; ++fn) {
                    acc[fm][fn] =
                        __builtin_amdgcn_mfma_f32_16x16x32_f16(af.v, bfrag[fn], acc[fm][fn], 0, 0, 0);
                }
            }
        }
    };

    stageB(0, step0);
    __syncthreads();
    for (int t = 0; t < nst; ++t) {
        if (t + 1 < nst) stageB((t + 1) & 1, step0 + t + 1);
        compute(t & 1);
        __syncthreads();
    }

    _Float16* Gks = G2h + (size_t)ks * BS * GG;
#pragma unroll
    for (int fm = 0; fm < 4; ++fm) {
#pragma unroll
        for (int fn = 0; fn < 4; ++fn) {
            int bs = bs0 + wm * 64 + fm * 16 + ((lane >> 4) << 2);
            int g = g0 + wn * 64 + fn * 16 + (lane & 15);
            _Float16* base = Gks + (size_t)bs * GG + g;
#pragma unroll
            for (int r = 0; r < 4; ++r) base[r * GG] = (_Float16)acc[fm][fn][r];
        }
    }
}

// ---------------- reduce fp16 K-split partials + biases -> Xg[bs][512] (fp32) ----------------
__global__ __launch_bounds__(256) void k_reduce(const _Float16* __restrict__ G2h,
                                                const float* __restrict__ b_ih,
                                                const float* __restrict__ b_hh,
                                                float* __restrict__ Xg) {
    int idx = blockIdx.x * 256 + threadIdx.x;  // 65536 slots of 8
    int e = idx * 8;
    int g = e & (GG - 1);
    float a[8];
#pragma unroll
    for (int i = 0; i < 8; ++i) a[i] = b_ih[g + i] + b_hh[g + i];
#pragma unroll
    for (int p = 0; p < KS; ++p) {
        f16x8 v = *(const f16x8*)&G2h[(size_t)p * BS * GG + e];
#pragma unroll
        for (int i = 0; i < 8; ++i) a[i] += (float)v[i];
    }
    float4 r0 = {a[0], a[1], a[2], a[3]};
    float4 r1 = {a[4], a[5], a[6], a[7]};
    *(float4*)&Xg[e] = r0;
    *(float4*)&Xg[e + 4] = r1;
}

// ---------------- LSTM: 16 blocks, 512 thr, quad-DPP reduce (r13, 47.6 us) ----------------
__global__ __launch_bounds__(512, 1) void k_lstm_shfl(const float* __restrict__ Xg,
                                                      const _Float16* __restrict__ whh_h,
                                                      const float* __restrict__ head_w,
                                                      const float* __restrict__ head_b,
                                                      float* __restrict__ out) {
    __shared__ __align__(16) _Float16 hb0[HH];
    __shared__ __align__(16) _Float16 hb1[HH];
    __shared__ __align__(16) float hf[HH];

    int tid = threadIdx.x;
    int b = blockIdx.x;
    int d = tid >> 2;   // 0..127
    int kc = tid & 3;   // 0..3
    int k0 = kc * 32;

    union U8 { f16x8 v; f16x2 h[4]; };

    U8 w8[4][4];
#pragma unroll
    for (int q = 0; q < 4; ++q)
#pragma unroll
        for (int j = 0; j < 4; ++j)
            w8[q][j].v = *(const f16x8*)&whh_h[(q * HH + d) * HH + k0 + j * 8];
#pragma unroll
    for (int q = 0; q < 4; ++q)
#pragma unroll
        for (int j = 0; j < 4; ++j)
            asm volatile("" : "+v"(w8[q][j].v));

    if (tid < HH) hb0[tid] = (_Float16)0.f;
    float c = 0.f;
    float xg[4];
#pragma unroll
    for (int q = 0; q < 4; ++q) xg[q] = Xg[(size_t)(b * SS) * GG + q * HH + d];
    __syncthreads();

    auto lstm_step = [&](const _Float16* hr, _Float16* hw, int t) {
        U8 hh[4];
#pragma unroll
        for (int j = 0; j < 4; ++j) hh[j].v = *(const f16x8*)&hr[k0 + j * 8];
        float acc[4] = {0.f, 0.f, 0.f, 0.f};
#pragma unroll
        for (int j = 0; j < 4; ++j)
#pragma unroll
            for (int p = 0; p < 4; ++p) {
#pragma unroll
                for (int q = 0; q < 4; ++q)
                    acc[q] = fdot2(hh[j].h[p], w8[q][j].h[p], acc[q]);
            }
#pragma unroll
        for (int q = 0; q < 4; ++q) {
            acc[q] = dpp_add<0xB1>(acc[q]);  // quad_perm xor 1
            acc[q] = dpp_add<0x4E>(acc[q]);  // quad_perm xor 2
        }
        float ig = acc[0] + xg[0];
        float fg = acc[1] + xg[1];
        float gg = acc[2] + xg[2];
        float og = acc[3] + xg[3];
        int tn = (t + 1) & 63;
#pragma unroll
        for (int q = 0; q < 4; ++q)
            xg[q] = Xg[(size_t)(b * SS + tn) * GG + q * HH + d];
        float sf = fast_sigmoid(fg);
        float u = __expf(-ig);
        float wv = __expf(-2.f * fabsf(gg));
        float st = copysignf((1.f - wv) * __builtin_amdgcn_rcpf((1.f + u) * (1.f + wv)), gg);
        c = sf * c + st;
        float u2 = __expf(-og);
        float w2 = __expf(-2.f * fabsf(c));
        float h = copysignf((1.f - w2) * __builtin_amdgcn_rcpf((1.f + u2) * (1.f + w2)), c);
        if (kc == 0) {
            hw[d] = (_Float16)h;
            if (t == SS - 1) hf[d] = h;
        }
        lds_barrier();
    };

    for (int tt = 0; tt < SS; tt += 2) {
        lstm_step(hb0, hb1, tt);
        lstm_step(hb1, hb0, tt + 1);
    }

    __syncthreads();
    if (tid < NN) {
        float a0 = head_b[tid], a1 = 0.f, a2 = 0.f, a3 = 0.f;
        const float4* w4 = (const float4*)&head_w[tid * HH];
        const float4* h4 = (const float4*)hf;
#pragma unroll
        for (int j4 = 0; j4 < 32; ++j4) {
            float4 wv = w4[j4];
            float4 hv = h4[j4];
            a0 = fmaf(wv.x, hv.x, a0);
            a1 = fmaf(wv.y, hv.y, a1);
            a2 = fmaf(wv.z, hv.z, a2);
            a3 = fmaf(wv.w, hv.w, a3);
        }
        out[b * NN + tid] = (a0 + a1) + (a2 + a3);
    }
}

// ---------------- launch ----------------
extern "C" void kernel_launch(void* const* d_in, const int* in_sizes, int n_in, void* d_out,
                              int out_size, void* d_ws, size_t ws_size, hipStream_t stream) {
    const float* x = (const float*)d_in[0];
    const int* ei = (const int*)d_in[1];  // integer inputs arrive as int32
    const float* gat_w = (const float*)d_in[2];
    const float* a_src = (const float*)d_in[3];
    const float* a_dst = (const float*)d_in[4];
    const float* gat_b = (const float*)d_in[5];
    const float* w_ih = (const float*)d_in[6];
    const float* w_hh = (const float*)d_in[7];
    const float* b_ih = (const float*)d_in[8];
    const float* b_hh = (const float*)d_in[9];
    const float* head_w = (const float*)d_in[10];
    const float* head_b = (const float*)d_in[11];
    float* out = (float*)d_out;

    char* ws = (char*)d_ws;
    float* xt = (float*)(ws + 0);                      // 2,048,000 (dead after k_gat)
    float* s = (float*)(ws + 2048000u);                // 2,048,000 (dead after k_gemm)
    _Float16* G2h = (_Float16*)(ws + 4096000u);        // 16*1024*512*2 = 16,777,216
    _Float16* whh_h = (_Float16*)(ws + 37650432u);     // 131,072
    _Float16* w_h = (_Float16*)(ws + 37912576u);       // 16,384,000
    char* base2 = ws + 54296576u;                      // misc 65,536
    int* offsets = (int*)(base2);
    int* esrc = (int*)(base2 + 4096);
    float* scal = (float*)(base2 + 45056);
    float* Xg = (float*)(ws + 0);                      // 2,097,152 [bs][512] — overlaps xt+s
                                                       // (both dead by k_reduce; stream-ordered)

    k_prep<<<2689, 512, 0, stream>>>(x, xt, w_hh, whh_h, w_ih, w_h,
                                     ei, gat_w, a_src, a_dst, offsets, esrc, scal);
    k_gat<<<dim3(BS / 256, NN), 256, 0, stream>>>(xt, offsets, esrc, scal, s);
    k_gemm_mfma<<<dim3(KS, 4, 8), 256, 0, stream>>>(w_h, s, gat_w, gat_b, G2h);
    k_reduce<<<256, 256, 0, stream>>>(G2h, b_ih, b_hh, Xg);
    k_lstm_shfl<<<NB, 512, 0, stream>>>(Xg, whh_h, head_w, head_b, out);
}